// Round 7
// baseline (465.727 us; speedup 1.0000x reference)
//
#include <hip/hip_runtime.h>

// ---------------------------------------------------------------------------
// DistributionShiftGAT: 3-layer GAT on MI355X (gfx950).
// R7: GEMM rewritten as barrier-free LDS-free register K-loop: per-wave A/B
//     MFMA fragments loaded directly from global (B is L2-resident 512KB,
//     A rows 64B-contiguous), double-buffered in registers, zero s_barrier /
//     vmcnt(0) drains in the hot loop. Fused attdot epilogue kept.
//     Agg / CSR / scan unchanged from R6.
// ---------------------------------------------------------------------------

#define NEG_SLOPE 0.2f

typedef __attribute__((ext_vector_type(8))) short short8;
typedef __attribute__((ext_vector_type(4))) float floatx4;

static __device__ __forceinline__ unsigned short f2bf(float f) {
    unsigned u = __float_as_uint(f);
    u = u + 0x7FFFu + ((u >> 16) & 1u);      // RNE
    return (unsigned short)(u >> 16);
}
static __device__ __forceinline__ float bf2f_lo(unsigned u) {
    return __uint_as_float(u << 16);
}
static __device__ __forceinline__ float bf2f_hi(unsigned u) {
    return __uint_as_float(u & 0xFFFF0000u);
}

// ---------------- casts ----------------

__global__ __launch_bounds__(256)
void cast_bf16_kernel(const float* __restrict__ in, unsigned short* __restrict__ out, int n4) {
    int i = blockIdx.x * 256 + threadIdx.x;
    if (i < n4) {
        float4 v = ((const float4*)in)[i];
        ushort4 o;
        o.x = f2bf(v.x); o.y = f2bf(v.y); o.z = f2bf(v.z); o.w = f2bf(v.w);
        ((ushort4*)out)[i] = o;
    }
}

// W [K,N] fp32 -> WT [N,K] bf16 (tiny)
__global__ __launch_bounds__(256)
void wt_kernel(const float* __restrict__ W, unsigned short* __restrict__ WT, int K, int N) {
    int idx = blockIdx.x * 256 + threadIdx.x;
    if (idx < K * N) {
        int k = idx / N, n = idx - k * N;
        WT[(size_t)n * K + k] = f2bf(W[idx]);
    }
}

// ---------------- CSR build ----------------

__global__ __launch_bounds__(256)
void init_counts_kernel(int* cursor, int N) {
    int i = blockIdx.x * 256 + threadIdx.x;
    if (i < N) cursor[i] = 1;            // self-loop contributes 1 per dst
}

__global__ __launch_bounds__(256)
void hist_kernel(const int* __restrict__ ei, int* cursor, int E) {
    int e = blockIdx.x * 256 + threadIdx.x;
    if (e < E) atomicAdd(&cursor[ei[E + e]], 1);   // ei[1][e] = dst
}

// parallel scan, step 1: per-1024-block sums
__global__ __launch_bounds__(1024)
void scan_bsum_kernel(const int* __restrict__ cursor, int* __restrict__ bsum, int N) {
    __shared__ int wsum[16];
    int tid = threadIdx.x, lane = tid & 63, w = tid >> 6;
    int i = blockIdx.x * 1024 + tid;
    int v = (i < N) ? cursor[i] : 0;
    #pragma unroll
    for (int off = 32; off; off >>= 1) v += __shfl_xor(v, off, 64);
    if (lane == 0) wsum[w] = v;
    __syncthreads();
    if (tid == 0) {
        int t = 0;
        #pragma unroll
        for (int k = 0; k < 16; ++k) t += wsum[k];
        bsum[blockIdx.x] = t;
    }
}

// step 2: single-wave exclusive scan of <=64 block sums; also writes row_ptr[N]
__global__ __launch_bounds__(64)
void scan_boffs_kernel(const int* __restrict__ bsum, int* __restrict__ boffs,
                       int NB, int* __restrict__ row_ptr, int N) {
    int lane = threadIdx.x;
    int v = (lane < NB) ? bsum[lane] : 0;
    int x = v;
    #pragma unroll
    for (int off = 1; off < 64; off <<= 1) {
        int t = __shfl_up(x, off, 64);
        if (lane >= off) x += t;
    }
    if (lane < NB) boffs[lane] = x - v;
    if (lane == 63) row_ptr[N] = x;      // grand total
}

// step 3: per-block inclusive scan + block offset -> exclusive scan out
__global__ __launch_bounds__(1024)
void scan_final_kernel(int* __restrict__ cursor, const int* __restrict__ boffs,
                       int* __restrict__ row_ptr, int N) {
    __shared__ int wsum[16];
    int tid = threadIdx.x, lane = tid & 63, w = tid >> 6;
    int i = blockIdx.x * 1024 + tid;
    int v = (i < N) ? cursor[i] : 0;
    int x = v;
    #pragma unroll
    for (int off = 1; off < 64; off <<= 1) {
        int t = __shfl_up(x, off, 64);
        if (lane >= off) x += t;
    }
    if (lane == 63) wsum[w] = x;
    __syncthreads();
    if (w == 0 && lane < 16) {
        int y = wsum[lane];
        #pragma unroll
        for (int off = 1; off < 16; off <<= 1) {
            int t = __shfl_up(y, off, 64);
            if (lane >= off) y += t;
        }
        wsum[lane] = y;
    }
    __syncthreads();
    int woff = (w == 0) ? 0 : wsum[w - 1];
    int ex = boffs[blockIdx.x] + woff + x - v;   // exclusive
    if (i < N) { row_ptr[i] = ex; cursor[i] = ex; }
}

__global__ __launch_bounds__(256)
void scatter_kernel(const int* __restrict__ ei, int* cursor,
                    int* __restrict__ csr_src, int E, int N) {
    int i = blockIdx.x * 256 + threadIdx.x;
    if (i < E) {
        int s = ei[i], d = ei[E + i];
        int pos = atomicAdd(&cursor[d], 1);
        csr_src[pos] = s;
    } else if (i < E + N) {
        int n = i - E;
        int pos = atomicAdd(&cursor[n], 1);
        csr_src[pos] = n;                // self loop
    }
}

// ---------------- bf16 MFMA GEMM + fused attention dots ----------------
// C[M,Nn]bf16 = A[M,K]bf16 @ BT[Nn,K]^T. 128x128 tile, 4 waves, 64x64/wave.
// LDS-FREE, BARRIER-FREE K-loop: each wave loads its A/B fragments directly
// from global (B <=512KB, L2-resident everywhere; A 64B-contiguous per row),
// register double-buffered; the compiler inserts fine-grained vmcnt waits,
// no s_barrier / vmcnt(0) drain until the epilogue.
// Block x covers exactly one head (Nn = H*128); epilogue computes
// a_src/a_dst[row,head] from the fp32 accumulators.

__global__ __launch_bounds__(256)
void mfma_gemm_kernel(const unsigned short* __restrict__ A,
                      const unsigned short* __restrict__ BT,
                      unsigned short* __restrict__ C,
                      const float* __restrict__ att_src,
                      const float* __restrict__ att_dst,
                      float* __restrict__ a_srcO, float* __restrict__ a_dstO,
                      int H, int M, int Nn, int K) {
    __shared__ float psum[2][128];
    __shared__ float pdsum[2][128];
    const int tid = threadIdx.x;
    const int m0 = blockIdx.y * 128;
    const int n0 = blockIdx.x * 128;
    const int head = blockIdx.x;               // Nn == H*128
    const int lane = tid & 63, wave = tid >> 6;
    const int wm = (wave & 1) * 64, wn = (wave >> 1) * 64;
    const int quad = lane >> 4, rr = lane & 15;

    // per-lane fragment base pointers (16B-aligned: K%32==0, quad*8 elems)
    const unsigned short* Ap[4];
    const unsigned short* Bp[4];
    #pragma unroll
    for (int mi = 0; mi < 4; ++mi)
        Ap[mi] = A + (size_t)min(m0 + wm + mi * 16 + rr, M - 1) * K + quad * 8;
    #pragma unroll
    for (int ni = 0; ni < 4; ++ni)
        Bp[ni] = BT + (size_t)(n0 + wn + ni * 16 + rr) * K + quad * 8;

    floatx4 acc[4][4] = {};
    short8 a0[4], b0[4], a1[4], b1[4];

#define LOADF(AF, BF, k0)                                                     \
    { _Pragma("unroll")                                                       \
      for (int q = 0; q < 4; ++q) AF[q] = *(const short8*)(Ap[q] + (k0));     \
      _Pragma("unroll")                                                       \
      for (int q = 0; q < 4; ++q) BF[q] = *(const short8*)(Bp[q] + (k0)); }

#define MFMAS(AF, BF)                                                         \
    { _Pragma("unroll")                                                       \
      for (int mi = 0; mi < 4; ++mi)                                          \
          _Pragma("unroll")                                                   \
          for (int ni = 0; ni < 4; ++ni)                                      \
              acc[mi][ni] = __builtin_amdgcn_mfma_f32_16x16x32_bf16(          \
                  AF[mi], BF[ni], acc[mi][ni], 0, 0, 0); }

    LOADF(a0, b0, 0);
    const int nk = K >> 5;                 // 8 or 16 (even)
    int k = 0;
    for (int c = 0; c < nk; c += 2) {
        if (c + 1 < nk) LOADF(a1, b1, k + 32);
        MFMAS(a0, b0);
        if (c + 2 < nk) LOADF(a0, b0, k + 64);
        MFMAS(a1, b1);
        k += 64;
    }
#undef LOADF
#undef MFMAS

    // ---- h store (bf16), C/D layout: col=lane&15, row=quad*4+reg ----
    #pragma unroll
    for (int mi = 0; mi < 4; ++mi) {
        #pragma unroll
        for (int ni = 0; ni < 4; ++ni) {
            int col = n0 + wn + ni * 16 + rr;
            #pragma unroll
            for (int r = 0; r < 4; ++r) {
                int row = m0 + wm + mi * 16 + quad * 4 + r;
                if (row < M) C[(size_t)row * Nn + col] = f2bf(acc[mi][ni][r]);
            }
        }
    }

    // ---- fused attention dots ----
    float ats[4], atd[4];
    #pragma unroll
    for (int ni = 0; ni < 4; ++ni) {
        int c = wn + ni * 16 + rr;          // channel within head
        ats[ni] = att_src[head * 128 + c];
        atd[ni] = att_dst[head * 128 + c];
    }
    const int wnh = wn >> 6;
    #pragma unroll
    for (int mi = 0; mi < 4; ++mi) {
        #pragma unroll
        for (int r = 0; r < 4; ++r) {
            float ps = 0.f, pd = 0.f;
            #pragma unroll
            for (int ni = 0; ni < 4; ++ni) {
                ps += ats[ni] * acc[mi][ni][r];
                pd += atd[ni] * acc[mi][ni][r];
            }
            #pragma unroll
            for (int off = 1; off < 16; off <<= 1) {
                ps += __shfl_xor(ps, off, 64);
                pd += __shfl_xor(pd, off, 64);
            }
            if (rr == 0) {
                int row = wm + mi * 16 + quad * 4 + r;   // local row
                psum[wnh][row] = ps;
                pdsum[wnh][row] = pd;
            }
        }
    }
    __syncthreads();
    if (tid < 128) {
        int gr = m0 + tid;
        if (gr < M) {
            a_srcO[(size_t)gr * H + head] = psum[0][tid] + psum[1][tid];
            a_dstO[(size_t)gr * H + head] = pdsum[0][tid] + pdsum[1][tid];
        }
    }
}

// ---------------- per-dst-node softmax + aggregation ----------------
// One WAVE per dst node. Single pass: exp(e) without max subtraction
// (logits O(1): identical ratio, fp32-safe). Depth-4 software pipeline on the
// row gathers; CSR index chain scalarized via readfirstlane. No LDS/barriers.

template<int F, int H, bool RELU, bool BF16OUT>
__global__ __launch_bounds__(256)
void agg_kernel(const unsigned* __restrict__ hfeat, const float* __restrict__ a_src,
                const float* __restrict__ a_dst, const int* __restrict__ row_ptr,
                const int* __restrict__ csr_src, const float* __restrict__ bias,
                void* __restrict__ out_v, int N) {
    constexpr int C = 128;
    constexpr int UPL = F / 128;             // uints per lane: 4 or 1
    constexpr int RU = F / 2;                // uints per row
    const int wave = threadIdx.x >> 6, lane = threadIdx.x & 63;
    const int n = blockIdx.x * 4 + wave;
    if (n >= N) return;
    const int begin = __builtin_amdgcn_readfirstlane(row_ptr[n]);
    const int deg = __builtin_amdgcn_readfirstlane(row_ptr[n + 1]) - begin;
    const int myh = (2 * UPL * lane) / C;
    const float adst = a_dst[n * H + myh];

    float acc[2 * UPL];
    #pragma unroll
    for (int j = 0; j < 2 * UPL; ++j) acc[j] = 0.f;
    float dacc = 0.f;

    unsigned u0[UPL], u1[UPL], u2[UPL], u3[UPL];
    float av0 = 0.f, av1 = 0.f, av2 = 0.f, av3 = 0.f;

#define LOADSLOT(idx, U, AV)                                              \
    {                                                                     \
        int s_ = __builtin_amdgcn_readfirstlane(csr_src[begin + (idx)]);  \
        if (UPL == 4) {                                                   \
            uint4 t_ = ((const uint4*)(hfeat + (size_t)s_ * RU))[lane];   \
            U[0] = t_.x; U[1] = t_.y; U[2] = t_.z; U[3] = t_.w;           \
        } else {                                                          \
            U[0] = hfeat[(size_t)s_ * RU + lane];                         \
        }                                                                 \
        AV = a_src[s_ * H + myh];                                         \
    }

#define CONSUME(U, AV)                                                    \
    {                                                                     \
        float e_ = AV + adst;                                             \
        e_ = e_ > 0.f ? e_ : NEG_SLOPE * e_;                              \
        float ex_ = __expf(e_);                                           \
        dacc += ex_;                                                      \
        _Pragma("unroll")                                                 \
        for (int q_ = 0; q_ < UPL; ++q_) {                                \
            acc[2 * q_]     += ex_ * bf2f_lo(U[q_]);                      \
            acc[2 * q_ + 1] += ex_ * bf2f_hi(U[q_]);                      \
        }                                                                 \
    }

    LOADSLOT(0, u0, av0);
    if (deg > 1) LOADSLOT(1, u1, av1);
    if (deg > 2) LOADSLOT(2, u2, av2);
    if (deg > 3) LOADSLOT(3, u3, av3);
    int i = 0;
    for (; i + 8 <= deg; i += 4) {
        CONSUME(u0, av0); LOADSLOT(i + 4, u0, av0);
        CONSUME(u1, av1); LOADSLOT(i + 5, u1, av1);
        CONSUME(u2, av2); LOADSLOT(i + 6, u2, av2);
        CONSUME(u3, av3); LOADSLOT(i + 7, u3, av3);
    }
    int rem = deg - i;                       // 1..7
    CONSUME(u0, av0); if (rem > 4) LOADSLOT(i + 4, u0, av0);
    if (rem > 1) { CONSUME(u1, av1); if (rem > 5) LOADSLOT(i + 5, u1, av1); }
    if (rem > 2) { CONSUME(u2, av2); if (rem > 6) LOADSLOT(i + 6, u2, av2); }
    if (rem > 3) CONSUME(u3, av3);
    if (rem > 4) CONSUME(u0, av0);
    if (rem > 5) CONSUME(u1, av1);
    if (rem > 6) CONSUME(u2, av2);
#undef LOADSLOT
#undef CONSUME

    // epilogue: lane owns channels [2*UPL*lane, 2*UPL*lane + 2*UPL)
    float inv = 1.f / dacc;
    const int cb = 2 * UPL * lane;
    if (BF16OUT) {
        unsigned pk[UPL];
        #pragma unroll
        for (int q = 0; q < UPL; ++q) {
            float v0 = acc[2 * q] * inv + bias[cb + 2 * q];
            float v1 = acc[2 * q + 1] * inv + bias[cb + 2 * q + 1];
            if (RELU) { v0 = fmaxf(v0, 0.f); v1 = fmaxf(v1, 0.f); }
            pk[q] = (unsigned)f2bf(v0) | ((unsigned)f2bf(v1) << 16);
        }
        if (UPL == 4) {
            uint4 t; t.x = pk[0]; t.y = pk[1]; t.z = pk[2]; t.w = pk[3];
            ((uint4*)((unsigned*)out_v + (size_t)n * RU))[lane] = t;
        } else {
            ((unsigned*)out_v)[(size_t)n * RU + lane] = pk[0];
        }
    } else {
        #pragma unroll
        for (int q = 0; q < UPL; ++q) {
            float v0 = acc[2 * q] * inv + bias[cb + 2 * q];
            float v1 = acc[2 * q + 1] * inv + bias[cb + 2 * q + 1];
            if (RELU) { v0 = fmaxf(v0, 0.f); v1 = fmaxf(v1, 0.f); }
            float2 o; o.x = v0; o.y = v1;
            ((float2*)((float*)out_v + (size_t)n * F))[UPL * lane + q] = o;
        }
    }
}

// ---------------- host launch ----------------

extern "C" void kernel_launch(void* const* d_in, const int* in_sizes, int n_in,
                              void* d_out, int out_size, void* d_ws, size_t ws_size,
                              hipStream_t stream) {
    const float* x        = (const float*)d_in[0];
    const int*   ei       = (const int*)  d_in[1];
    const float* W1       = (const float*)d_in[2];
    const float* att_src1 = (const float*)d_in[3];
    const float* att_dst1 = (const float*)d_in[4];
    const float* b1       = (const float*)d_in[5];
    const float* W2       = (const float*)d_in[6];
    const float* att_src2 = (const float*)d_in[7];
    const float* att_dst2 = (const float*)d_in[8];
    const float* b2       = (const float*)d_in[9];
    const float* W3       = (const float*)d_in[10];
    const float* att_src3 = (const float*)d_in[11];
    const float* att_dst3 = (const float*)d_in[12];
    const float* b3       = (const float*)d_in[13];

    const int IN_FEATS = 256;
    const int N = in_sizes[0] / IN_FEATS;   // 30000
    const int E = in_sizes[1] / 2;          // 480000
    const int ET = E + N;
    const int NB = (N + 1023) / 1024;       // scan blocks (30)

    // workspace layout
    char* p = (char*)d_ws;
    unsigned short* h_bf    = (unsigned short*)p; p += (size_t)N * 512 * sizeof(unsigned short);
    unsigned short* act_bf  = (unsigned short*)p; p += (size_t)N * 512 * sizeof(unsigned short);
    unsigned short* x_bf    = (unsigned short*)p; p += (size_t)N * 256 * sizeof(unsigned short);
    float*          a_src   = (float*)p;          p += (size_t)N * 4 * sizeof(float);
    float*          a_dst   = (float*)p;          p += (size_t)N * 4 * sizeof(float);
    unsigned short* W_T     = (unsigned short*)p; p += (size_t)512 * 512 * sizeof(unsigned short);
    int*            row_ptr = (int*)p;            p += ((size_t)N + 16) * sizeof(int);
    int*            cursor  = (int*)p;            p += ((size_t)N + 16) * sizeof(int);
    int*            bsum    = (int*)p;            p += 64 * sizeof(int);
    int*            boffs   = (int*)p;            p += 64 * sizeof(int);
    int*            csr_src = (int*)p;            p += (size_t)ET * sizeof(int);

    // ---- CSR build (shared across layers) ----
    init_counts_kernel<<<(N + 255) / 256, 256, 0, stream>>>(cursor, N);
    hist_kernel<<<(E + 255) / 256, 256, 0, stream>>>(ei, cursor, E);
    scan_bsum_kernel<<<NB, 1024, 0, stream>>>(cursor, bsum, N);
    scan_boffs_kernel<<<1, 64, 0, stream>>>(bsum, boffs, NB, row_ptr, N);
    scan_final_kernel<<<NB, 1024, 0, stream>>>(cursor, boffs, row_ptr, N);
    scatter_kernel<<<(E + N + 255) / 256, 256, 0, stream>>>(ei, cursor, csr_src, E, N);

    // ---- x -> bf16 ----
    {
        int n4 = N * 256 / 4;
        cast_bf16_kernel<<<(n4 + 255) / 256, 256, 0, stream>>>(x, x_bf, n4);
    }

    const int MB = (N + 127) / 128;
    const int NB4 = (N + 3) / 4;

    // ---- Layer 1: 256 -> 4x128 concat + relu (h bf16) ----
    wt_kernel<<<(256 * 512 + 255) / 256, 256, 0, stream>>>(W1, W_T, 256, 512);
    mfma_gemm_kernel<<<dim3(4, MB), 256, 0, stream>>>(x_bf, W_T, h_bf, att_src1, att_dst1, a_src, a_dst, 4, N, 512, 256);
    agg_kernel<512, 4, true, true><<<NB4, 256, 0, stream>>>((const unsigned*)h_bf, a_src, a_dst, row_ptr, csr_src, b1, act_bf, N);

    // ---- Layer 2: 512 -> 4x128 concat + relu (h bf16) ----
    wt_kernel<<<(512 * 512 + 255) / 256, 256, 0, stream>>>(W2, W_T, 512, 512);
    mfma_gemm_kernel<<<dim3(4, MB), 256, 0, stream>>>(act_bf, W_T, h_bf, att_src2, att_dst2, a_src, a_dst, 4, N, 512, 512);
    agg_kernel<512, 4, true, true><<<NB4, 256, 0, stream>>>((const unsigned*)h_bf, a_src, a_dst, row_ptr, csr_src, b2, act_bf, N);

    // ---- Layer 3: 512 -> 1x128 (h bf16), fp32 out, no relu ----
    wt_kernel<<<(512 * 128 + 255) / 256, 256, 0, stream>>>(W3, W_T, 512, 128);
    mfma_gemm_kernel<<<dim3(1, MB), 256, 0, stream>>>(act_bf, W_T, h_bf, att_src3, att_dst3, a_src, a_dst, 1, N, 128, 512);
    agg_kernel<128, 1, false, false><<<NB4, 256, 0, stream>>>((const unsigned*)h_bf, a_src, a_dst, row_ptr, csr_src, b3, d_out, N);
}

// Round 8
// 453.970 us; speedup vs baseline: 1.0259x; 1.0259x over previous
//
#include <hip/hip_runtime.h>

// ---------------------------------------------------------------------------
// DistributionShiftGAT: 3-layer GAT on MI355X (gfx950).
// R8: GEMM reverted to R6 (LDS + global_load_lds; R7's LDS-free variant hit
//     16-cacheline/instr fragment gathers and regressed). Big aggs rewritten
//     as wave-per-(node,head) with XCD-affinity head swizzle (blockIdx&7 ->
//     head): per-XCD gather working set 30.7MB -> 7.7MB (~L2-resident).
// ---------------------------------------------------------------------------

#define NEG_SLOPE 0.2f

typedef __attribute__((ext_vector_type(8))) short short8;
typedef __attribute__((ext_vector_type(4))) float floatx4;

static __device__ __forceinline__ unsigned short f2bf(float f) {
    unsigned u = __float_as_uint(f);
    u = u + 0x7FFFu + ((u >> 16) & 1u);      // RNE
    return (unsigned short)(u >> 16);
}
static __device__ __forceinline__ float bf2f_lo(unsigned u) {
    return __uint_as_float(u << 16);
}
static __device__ __forceinline__ float bf2f_hi(unsigned u) {
    return __uint_as_float(u & 0xFFFF0000u);
}

// async global->LDS, 16B per lane; LDS fills base + lane*16 (wave-uniform base)
static __device__ __forceinline__ void async_copy16(const void* g, void* l) {
    __builtin_amdgcn_global_load_lds(
        (const __attribute__((address_space(1))) unsigned int*)g,
        (__attribute__((address_space(3))) unsigned int*)l, 16, 0, 0);
}

// ---------------- casts ----------------

__global__ __launch_bounds__(256)
void cast_bf16_kernel(const float* __restrict__ in, unsigned short* __restrict__ out, int n4) {
    int i = blockIdx.x * 256 + threadIdx.x;
    if (i < n4) {
        float4 v = ((const float4*)in)[i];
        ushort4 o;
        o.x = f2bf(v.x); o.y = f2bf(v.y); o.z = f2bf(v.z); o.w = f2bf(v.w);
        ((ushort4*)out)[i] = o;
    }
}

// W [K,N] fp32 -> WT [N,K] bf16 (tiny)
__global__ __launch_bounds__(256)
void wt_kernel(const float* __restrict__ W, unsigned short* __restrict__ WT, int K, int N) {
    int idx = blockIdx.x * 256 + threadIdx.x;
    if (idx < K * N) {
        int k = idx / N, n = idx - k * N;
        WT[(size_t)n * K + k] = f2bf(W[idx]);
    }
}

// ---------------- CSR build ----------------

__global__ __launch_bounds__(256)
void init_counts_kernel(int* cursor, int N) {
    int i = blockIdx.x * 256 + threadIdx.x;
    if (i < N) cursor[i] = 1;            // self-loop contributes 1 per dst
}

__global__ __launch_bounds__(256)
void hist_kernel(const int* __restrict__ ei, int* cursor, int E) {
    int e = blockIdx.x * 256 + threadIdx.x;
    if (e < E) atomicAdd(&cursor[ei[E + e]], 1);   // ei[1][e] = dst
}

// parallel scan, step 1: per-1024-block sums
__global__ __launch_bounds__(1024)
void scan_bsum_kernel(const int* __restrict__ cursor, int* __restrict__ bsum, int N) {
    __shared__ int wsum[16];
    int tid = threadIdx.x, lane = tid & 63, w = tid >> 6;
    int i = blockIdx.x * 1024 + tid;
    int v = (i < N) ? cursor[i] : 0;
    #pragma unroll
    for (int off = 32; off; off >>= 1) v += __shfl_xor(v, off, 64);
    if (lane == 0) wsum[w] = v;
    __syncthreads();
    if (tid == 0) {
        int t = 0;
        #pragma unroll
        for (int k = 0; k < 16; ++k) t += wsum[k];
        bsum[blockIdx.x] = t;
    }
}

// step 2: single-wave exclusive scan of <=64 block sums; also writes row_ptr[N]
__global__ __launch_bounds__(64)
void scan_boffs_kernel(const int* __restrict__ bsum, int* __restrict__ boffs,
                       int NB, int* __restrict__ row_ptr, int N) {
    int lane = threadIdx.x;
    int v = (lane < NB) ? bsum[lane] : 0;
    int x = v;
    #pragma unroll
    for (int off = 1; off < 64; off <<= 1) {
        int t = __shfl_up(x, off, 64);
        if (lane >= off) x += t;
    }
    if (lane < NB) boffs[lane] = x - v;
    if (lane == 63) row_ptr[N] = x;      // grand total
}

// step 3: per-block inclusive scan + block offset -> exclusive scan out
__global__ __launch_bounds__(1024)
void scan_final_kernel(int* __restrict__ cursor, const int* __restrict__ boffs,
                       int* __restrict__ row_ptr, int N) {
    __shared__ int wsum[16];
    int tid = threadIdx.x, lane = tid & 63, w = tid >> 6;
    int i = blockIdx.x * 1024 + tid;
    int v = (i < N) ? cursor[i] : 0;
    int x = v;
    #pragma unroll
    for (int off = 1; off < 64; off <<= 1) {
        int t = __shfl_up(x, off, 64);
        if (lane >= off) x += t;
    }
    if (lane == 63) wsum[w] = x;
    __syncthreads();
    if (w == 0 && lane < 16) {
        int y = wsum[lane];
        #pragma unroll
        for (int off = 1; off < 16; off <<= 1) {
            int t = __shfl_up(y, off, 64);
            if (lane >= off) y += t;
        }
        wsum[lane] = y;
    }
    __syncthreads();
    int woff = (w == 0) ? 0 : wsum[w - 1];
    int ex = boffs[blockIdx.x] + woff + x - v;   // exclusive
    if (i < N) { row_ptr[i] = ex; cursor[i] = ex; }
}

__global__ __launch_bounds__(256)
void scatter_kernel(const int* __restrict__ ei, int* cursor,
                    int* __restrict__ csr_src, int E, int N) {
    int i = blockIdx.x * 256 + threadIdx.x;
    if (i < E) {
        int s = ei[i], d = ei[E + i];
        int pos = atomicAdd(&cursor[d], 1);
        csr_src[pos] = s;
    } else if (i < E + N) {
        int n = i - E;
        int pos = atomicAdd(&cursor[n], 1);
        csr_src[pos] = n;                // self loop
    }
}

// ---------------- bf16 MFMA GEMM + fused attention dots (R6 version) --------
// C[M,Nn]bf16 = A[M,K]bf16 @ BT[Nn,K]^T. 128x128 tile, BK=32, 4 waves.
// LDS staging via global_load_lds (16B/lane), XOR-swizzled (conflict-free).
// NOTE: R7 tried an LDS-free register K-loop (direct global fragment loads);
// it regressed 422->466us: quad-group lanes read 16 rows 1KB apart per
// dwordx4 (16 cachelines/instr) and B was re-read per wave. Keep LDS staging.
// Block x covers one head; epilogue computes a_src/a_dst[row,head].

__global__ __launch_bounds__(256)
void mfma_gemm_kernel(const unsigned short* __restrict__ A,
                      const unsigned short* __restrict__ BT,
                      unsigned short* __restrict__ C,
                      const float* __restrict__ att_src,
                      const float* __restrict__ att_dst,
                      float* __restrict__ a_srcO, float* __restrict__ a_dstO,
                      int H, int M, int Nn, int K) {
    __shared__ unsigned short As[128 * 32];
    __shared__ unsigned short Bs[128 * 32];
    __shared__ float psum[2][128];
    __shared__ float pdsum[2][128];
    const int tid = threadIdx.x;
    const int m0 = blockIdx.y * 128;
    const int n0 = blockIdx.x * 128;
    const int head = blockIdx.x;               // Nn == H*128
    const int lane = tid & 63, wave = tid >> 6;
    const int wm = (wave & 1) * 64, wn = (wave >> 1) * 64;
    const int quad = lane >> 4, rr = lane & 15;

    const int r16 = lane >> 2;
    const int phys = lane & 3;
    const int rowL0 = wave * 32 + r16;
    const int rowL1 = wave * 32 + 16 + r16;
    const int seg0 = phys ^ ((rowL0 >> 1) & 3);
    const int seg1 = phys ^ ((rowL1 >> 1) & 3);
    const int gmA0 = min(m0 + rowL0, M - 1);
    const int gmA1 = min(m0 + rowL1, M - 1);
    const int gnB0 = n0 + rowL0;
    const int gnB1 = n0 + rowL1;
    unsigned short* ldsA0 = As + (wave * 32) * 32;
    unsigned short* ldsA1 = As + (wave * 32 + 16) * 32;
    unsigned short* ldsB0 = Bs + (wave * 32) * 32;
    unsigned short* ldsB1 = Bs + (wave * 32 + 16) * 32;

    const int swz = quad ^ ((rr >> 1) & 3);

    floatx4 acc[4][4] = {};

    for (int k0 = 0; k0 < K; k0 += 32) {
        async_copy16(A  + (size_t)gmA0 * K + k0 + seg0 * 8, ldsA0);
        async_copy16(A  + (size_t)gmA1 * K + k0 + seg1 * 8, ldsA1);
        async_copy16(BT + (size_t)gnB0 * K + k0 + seg0 * 8, ldsB0);
        async_copy16(BT + (size_t)gnB1 * K + k0 + seg1 * 8, ldsB1);
        __syncthreads();

        short8 af[4], bf[4];
        #pragma unroll
        for (int mi = 0; mi < 4; ++mi)
            af[mi] = *(const short8*)(As + (wm + mi * 16 + rr) * 32 + swz * 8);
        #pragma unroll
        for (int ni = 0; ni < 4; ++ni)
            bf[ni] = *(const short8*)(Bs + (wn + ni * 16 + rr) * 32 + swz * 8);
        #pragma unroll
        for (int mi = 0; mi < 4; ++mi)
            #pragma unroll
            for (int ni = 0; ni < 4; ++ni)
                acc[mi][ni] = __builtin_amdgcn_mfma_f32_16x16x32_bf16(
                    af[mi], bf[ni], acc[mi][ni], 0, 0, 0);
        __syncthreads();
    }

    // ---- h store (bf16), C/D layout: col=lane&15, row=quad*4+reg ----
    #pragma unroll
    for (int mi = 0; mi < 4; ++mi) {
        #pragma unroll
        for (int ni = 0; ni < 4; ++ni) {
            int col = n0 + wn + ni * 16 + rr;
            #pragma unroll
            for (int r = 0; r < 4; ++r) {
                int row = m0 + wm + mi * 16 + quad * 4 + r;
                if (row < M) C[(size_t)row * Nn + col] = f2bf(acc[mi][ni][r]);
            }
        }
    }

    // ---- fused attention dots ----
    float ats[4], atd[4];
    #pragma unroll
    for (int ni = 0; ni < 4; ++ni) {
        int c = wn + ni * 16 + rr;          // channel within head
        ats[ni] = att_src[head * 128 + c];
        atd[ni] = att_dst[head * 128 + c];
    }
    const int wnh = wn >> 6;
    #pragma unroll
    for (int mi = 0; mi < 4; ++mi) {
        #pragma unroll
        for (int r = 0; r < 4; ++r) {
            float ps = 0.f, pd = 0.f;
            #pragma unroll
            for (int ni = 0; ni < 4; ++ni) {
                ps += ats[ni] * acc[mi][ni][r];
                pd += atd[ni] * acc[mi][ni][r];
            }
            #pragma unroll
            for (int off = 1; off < 16; off <<= 1) {
                ps += __shfl_xor(ps, off, 64);
                pd += __shfl_xor(pd, off, 64);
            }
            if (rr == 0) {
                int row = wm + mi * 16 + quad * 4 + r;   // local row
                psum[wnh][row] = ps;
                pdsum[wnh][row] = pd;
            }
        }
    }
    __syncthreads();
    if (tid < 128) {
        int gr = m0 + tid;
        if (gr < M) {
            a_srcO[(size_t)gr * H + head] = psum[0][tid] + psum[1][tid];
            a_dstO[(size_t)gr * H + head] = pdsum[0][tid] + pdsum[1][tid];
        }
    }
}

// ---------------- head-sliced softmax + aggregation (H=4, F=512) ------------
// One WAVE per (dst node, head); lane covers one uint (2 ch) of the head's
// 256B slice. blockIdx&7 -> (head, node-half): the %8 XCD round-robin
// heuristic gives each XCD <=2 heads -> per-XCD gather working set 7.7MB
// (~L2-resident) instead of the full 30.7MB table. Single-pass exp (logits
// O(1)); depth-4 pipelined gathers; scalarized CSR chain; no LDS/barriers.

template<bool RELU>
__global__ __launch_bounds__(256)
void agg_slice_kernel(const unsigned* __restrict__ hfeat, const float* __restrict__ a_src,
                      const float* __restrict__ a_dst, const int* __restrict__ row_ptr,
                      const int* __restrict__ csr_src, const float* __restrict__ bias,
                      unsigned* __restrict__ out, int N) {
    constexpr int RU = 256;                  // uints per row (F=512)
    const int wave = threadIdx.x >> 6, lane = threadIdx.x & 63;
    const int slot = blockIdx.x & 7;
    const int head = slot & 3;
    const int n = (blockIdx.x >> 3) * 8 + wave * 2 + (slot >> 2);
    if (n >= N) return;
    const int begin = __builtin_amdgcn_readfirstlane(row_ptr[n]);
    const int deg = __builtin_amdgcn_readfirstlane(row_ptr[n + 1]) - begin;
    const float adst = a_dst[n * 4 + head];
    const unsigned* hsl = hfeat + head * 64 + lane;   // + s*RU

    float acc0 = 0.f, acc1 = 0.f, dacc = 0.f;
    unsigned u0 = 0, u1 = 0, u2 = 0, u3 = 0;
    float av0 = 0.f, av1 = 0.f, av2 = 0.f, av3 = 0.f;

#define LOADSLOT(idx, U, AV)                                              \
    {                                                                     \
        int s_ = __builtin_amdgcn_readfirstlane(csr_src[begin + (idx)]);  \
        U = hsl[(size_t)s_ * RU];                                         \
        AV = a_src[s_ * 4 + head];                                        \
    }

#define CONSUME(U, AV)                                                    \
    {                                                                     \
        float e_ = AV + adst;                                             \
        e_ = e_ > 0.f ? e_ : NEG_SLOPE * e_;                              \
        float ex_ = __expf(e_);                                           \
        dacc += ex_;                                                      \
        acc0 += ex_ * bf2f_lo(U);                                         \
        acc1 += ex_ * bf2f_hi(U);                                         \
    }

    LOADSLOT(0, u0, av0);
    if (deg > 1) LOADSLOT(1, u1, av1);
    if (deg > 2) LOADSLOT(2, u2, av2);
    if (deg > 3) LOADSLOT(3, u3, av3);
    int i = 0;
    for (; i + 8 <= deg; i += 4) {
        CONSUME(u0, av0); LOADSLOT(i + 4, u0, av0);
        CONSUME(u1, av1); LOADSLOT(i + 5, u1, av1);
        CONSUME(u2, av2); LOADSLOT(i + 6, u2, av2);
        CONSUME(u3, av3); LOADSLOT(i + 7, u3, av3);
    }
    int rem = deg - i;                       // 1..7
    CONSUME(u0, av0); if (rem > 4) LOADSLOT(i + 4, u0, av0);
    if (rem > 1) { CONSUME(u1, av1); if (rem > 5) LOADSLOT(i + 5, u1, av1); }
    if (rem > 2) { CONSUME(u2, av2); if (rem > 6) LOADSLOT(i + 6, u2, av2); }
    if (rem > 3) CONSUME(u3, av3);
    if (rem > 4) CONSUME(u0, av0);
    if (rem > 5) CONSUME(u1, av1);
    if (rem > 6) CONSUME(u2, av2);
#undef LOADSLOT
#undef CONSUME

    float inv = 1.f / dacc;
    int c = head * 128 + 2 * lane;
    float v0 = acc0 * inv + bias[c];
    float v1 = acc1 * inv + bias[c + 1];
    if (RELU) { v0 = fmaxf(v0, 0.f); v1 = fmaxf(v1, 0.f); }
    out[(size_t)n * RU + head * 64 + lane] =
        (unsigned)f2bf(v0) | ((unsigned)f2bf(v1) << 16);
}

// ---------------- generic agg (layer 3: H=1, F=128, fp32 out) ---------------

template<int F, int H, bool RELU, bool BF16OUT>
__global__ __launch_bounds__(256)
void agg_kernel(const unsigned* __restrict__ hfeat, const float* __restrict__ a_src,
                const float* __restrict__ a_dst, const int* __restrict__ row_ptr,
                const int* __restrict__ csr_src, const float* __restrict__ bias,
                void* __restrict__ out_v, int N) {
    constexpr int UPL = F / 128;             // uints per lane
    constexpr int RU = F / 2;                // uints per row
    const int wave = threadIdx.x >> 6, lane = threadIdx.x & 63;
    const int n = blockIdx.x * 4 + wave;
    if (n >= N) return;
    const int begin = __builtin_amdgcn_readfirstlane(row_ptr[n]);
    const int deg = __builtin_amdgcn_readfirstlane(row_ptr[n + 1]) - begin;
    const int myh = (2 * UPL * lane) / 128;
    const float adst = a_dst[n * H + myh];

    float acc[2 * UPL];
    #pragma unroll
    for (int j = 0; j < 2 * UPL; ++j) acc[j] = 0.f;
    float dacc = 0.f;

    unsigned u0[UPL], u1[UPL], u2[UPL], u3[UPL];
    float av0 = 0.f, av1 = 0.f, av2 = 0.f, av3 = 0.f;

#define LOADSLOT(idx, U, AV)                                              \
    {                                                                     \
        int s_ = __builtin_amdgcn_readfirstlane(csr_src[begin + (idx)]);  \
        if (UPL == 4) {                                                   \
            uint4 t_ = ((const uint4*)(hfeat + (size_t)s_ * RU))[lane];   \
            U[0] = t_.x; U[1] = t_.y; U[2] = t_.z; U[3] = t_.w;           \
        } else {                                                          \
            U[0] = hfeat[(size_t)s_ * RU + lane];                         \
        }                                                                 \
        AV = a_src[s_ * H + myh];                                         \
    }

#define CONSUME(U, AV)                                                    \
    {                                                                     \
        float e_ = AV + adst;                                             \
        e_ = e_ > 0.f ? e_ : NEG_SLOPE * e_;                              \
        float ex_ = __expf(e_);                                           \
        dacc += ex_;                                                      \
        _Pragma("unroll")                                                 \
        for (int q_ = 0; q_ < UPL; ++q_) {                                \
            acc[2 * q_]     += ex_ * bf2f_lo(U[q_]);                      \
            acc[2 * q_ + 1] += ex_ * bf2f_hi(U[q_]);                      \
        }                                                                 \
    }

    LOADSLOT(0, u0, av0);
    if (deg > 1) LOADSLOT(1, u1, av1);
    if (deg > 2) LOADSLOT(2, u2, av2);
    if (deg > 3) LOADSLOT(3, u3, av3);
    int i = 0;
    for (; i + 8 <= deg; i += 4) {
        CONSUME(u0, av0); LOADSLOT(i + 4, u0, av0);
        CONSUME(u1, av1); LOADSLOT(i + 5, u1, av1);
        CONSUME(u2, av2); LOADSLOT(i + 6, u2, av2);
        CONSUME(u3, av3); LOADSLOT(i + 7, u3, av3);
    }
    int rem = deg - i;                       // 1..7
    CONSUME(u0, av0); if (rem > 4) LOADSLOT(i + 4, u0, av0);
    if (rem > 1) { CONSUME(u1, av1); if (rem > 5) LOADSLOT(i + 5, u1, av1); }
    if (rem > 2) { CONSUME(u2, av2); if (rem > 6) LOADSLOT(i + 6, u2, av2); }
    if (rem > 3) CONSUME(u3, av3);
    if (rem > 4) CONSUME(u0, av0);
    if (rem > 5) CONSUME(u1, av1);
    if (rem > 6) CONSUME(u2, av2);
#undef LOADSLOT
#undef CONSUME

    float inv = 1.f / dacc;
    const int cb = 2 * UPL * lane;
    if (BF16OUT) {
        unsigned pk[UPL];
        #pragma unroll
        for (int q = 0; q < UPL; ++q) {
            float v0 = acc[2 * q] * inv + bias[cb + 2 * q];
            float v1 = acc[2 * q + 1] * inv + bias[cb + 2 * q + 1];
            if (RELU) { v0 = fmaxf(v0, 0.f); v1 = fmaxf(v1, 0.f); }
            pk[q] = (unsigned)f2bf(v0) | ((unsigned)f2bf(v1) << 16);
        }
        if (UPL == 4) {
            uint4 t; t.x = pk[0]; t.y = pk[1]; t.z = pk[2]; t.w = pk[3];
            ((uint4*)((unsigned*)out_v + (size_t)n * RU))[lane] = t;
        } else {
            ((unsigned*)out_v)[(size_t)n * RU + lane] = pk[0];
        }
    } else {
        #pragma unroll
        for (int q = 0; q < UPL; ++q) {
            float v0 = acc[2 * q] * inv + bias[cb + 2 * q];
            float v1 = acc[2 * q + 1] * inv + bias[cb + 2 * q + 1];
            if (RELU) { v0 = fmaxf(v0, 0.f); v1 = fmaxf(v1, 0.f); }
            float2 o; o.x = v0; o.y = v1;
            ((float2*)((float*)out_v + (size_t)n * F))[UPL * lane + q] = o;
        }
    }
}

// ---------------- host launch ----------------

extern "C" void kernel_launch(void* const* d_in, const int* in_sizes, int n_in,
                              void* d_out, int out_size, void* d_ws, size_t ws_size,
                              hipStream_t stream) {
    const float* x        = (const float*)d_in[0];
    const int*   ei       = (const int*)  d_in[1];
    const float* W1       = (const float*)d_in[2];
    const float* att_src1 = (const float*)d_in[3];
    const float* att_dst1 = (const float*)d_in[4];
    const float* b1       = (const float*)d_in[5];
    const float* W2       = (const float*)d_in[6];
    const float* att_src2 = (const float*)d_in[7];
    const float* att_dst2 = (const float*)d_in[8];
    const float* b2       = (const float*)d_in[9];
    const float* W3       = (const float*)d_in[10];
    const float* att_src3 = (const float*)d_in[11];
    const float* att_dst3 = (const float*)d_in[12];
    const float* b3       = (const float*)d_in[13];

    const int IN_FEATS = 256;
    const int N = in_sizes[0] / IN_FEATS;   // 30000
    const int E = in_sizes[1] / 2;          // 480000
    const int ET = E + N;
    const int NB = (N + 1023) / 1024;       // scan blocks (30)

    // workspace layout
    char* p = (char*)d_ws;
    unsigned short* h_bf    = (unsigned short*)p; p += (size_t)N * 512 * sizeof(unsigned short);
    unsigned short* act_bf  = (unsigned short*)p; p += (size_t)N * 512 * sizeof(unsigned short);
    unsigned short* x_bf    = (unsigned short*)p; p += (size_t)N * 256 * sizeof(unsigned short);
    float*          a_src   = (float*)p;          p += (size_t)N * 4 * sizeof(float);
    float*          a_dst   = (float*)p;          p += (size_t)N * 4 * sizeof(float);
    unsigned short* W_T     = (unsigned short*)p; p += (size_t)512 * 512 * sizeof(unsigned short);
    int*            row_ptr = (int*)p;            p += ((size_t)N + 16) * sizeof(int);
    int*            cursor  = (int*)p;            p += ((size_t)N + 16) * sizeof(int);
    int*            bsum    = (int*)p;            p += 64 * sizeof(int);
    int*            boffs   = (int*)p;            p += 64 * sizeof(int);
    int*            csr_src = (int*)p;            p += (size_t)ET * sizeof(int);

    // ---- CSR build (shared across layers) ----
    init_counts_kernel<<<(N + 255) / 256, 256, 0, stream>>>(cursor, N);
    hist_kernel<<<(E + 255) / 256, 256, 0, stream>>>(ei, cursor, E);
    scan_bsum_kernel<<<NB, 1024, 0, stream>>>(cursor, bsum, N);
    scan_boffs_kernel<<<1, 64, 0, stream>>>(bsum, boffs, NB, row_ptr, N);
    scan_final_kernel<<<NB, 1024, 0, stream>>>(cursor, boffs, row_ptr, N);
    scatter_kernel<<<(E + N + 255) / 256, 256, 0, stream>>>(ei, cursor, csr_src, E, N);

    // ---- x -> bf16 ----
    {
        int n4 = N * 256 / 4;
        cast_bf16_kernel<<<(n4 + 255) / 256, 256, 0, stream>>>(x, x_bf, n4);
    }

    const int MB = (N + 127) / 128;
    const int NB4 = (N + 3) / 4;
    const int NSL = ((N + 7) / 8) * 8;      // slice grid (head-sliced agg)

    // ---- Layer 1: 256 -> 4x128 concat + relu (h bf16) ----
    wt_kernel<<<(256 * 512 + 255) / 256, 256, 0, stream>>>(W1, W_T, 256, 512);
    mfma_gemm_kernel<<<dim3(4, MB), 256, 0, stream>>>(x_bf, W_T, h_bf, att_src1, att_dst1, a_src, a_dst, 4, N, 512, 256);
    agg_slice_kernel<true><<<NSL, 256, 0, stream>>>((const unsigned*)h_bf, a_src, a_dst, row_ptr, csr_src, b1, (unsigned*)act_bf, N);

    // ---- Layer 2: 512 -> 4x128 concat + relu (h bf16) ----
    wt_kernel<<<(512 * 512 + 255) / 256, 256, 0, stream>>>(W2, W_T, 512, 512);
    mfma_gemm_kernel<<<dim3(4, MB), 256, 0, stream>>>(act_bf, W_T, h_bf, att_src2, att_dst2, a_src, a_dst, 4, N, 512, 512);
    agg_slice_kernel<true><<<NSL, 256, 0, stream>>>((const unsigned*)h_bf, a_src, a_dst, row_ptr, csr_src, b2, (unsigned*)act_bf, N);

    // ---- Layer 3: 512 -> 1x128 (h bf16), fp32 out, no relu ----
    wt_kernel<<<(512 * 128 + 255) / 256, 256, 0, stream>>>(W3, W_T, 512, 128);
    mfma_gemm_kernel<<<dim3(1, MB), 256, 0, stream>>>(act_bf, W_T, h_bf, att_src3, att_dst3, a_src, a_dst, 1, N, 128, 512);
    agg_kernel<128, 1, false, false><<<NB4, 256, 0, stream>>>((const unsigned*)h_bf, a_src, a_dst, row_ptr, csr_src, b3, d_out, N);
}

// Round 9
// 415.755 us; speedup vs baseline: 1.1202x; 1.0919x over previous
//
#include <hip/hip_runtime.h>

// ---------------------------------------------------------------------------
// DistributionShiftGAT: 3-layer GAT on MI355X (gfx950).
// R9: agg reverted to R6 wave-per-node (R8 head-slice cut FETCH 241->176MB but
//     regressed 75->95us: 4x exp work + 4B/lane loads -> FETCH is not the
//     binding resource; 75us is agg's practical floor). Dispatch-count cut
//     16->13: init_counts -> hipMemsetAsync + "+i" self-loop trick in scan;
//     cast + all three W transposes fused into one prep kernel.
// ---------------------------------------------------------------------------

#define NEG_SLOPE 0.2f

typedef __attribute__((ext_vector_type(8))) short short8;
typedef __attribute__((ext_vector_type(4))) float floatx4;

static __device__ __forceinline__ unsigned short f2bf(float f) {
    unsigned u = __float_as_uint(f);
    u = u + 0x7FFFu + ((u >> 16) & 1u);      // RNE
    return (unsigned short)(u >> 16);
}
static __device__ __forceinline__ float bf2f_lo(unsigned u) {
    return __uint_as_float(u << 16);
}
static __device__ __forceinline__ float bf2f_hi(unsigned u) {
    return __uint_as_float(u & 0xFFFF0000u);
}

// async global->LDS, 16B per lane; LDS fills base + lane*16 (wave-uniform base)
static __device__ __forceinline__ void async_copy16(const void* g, void* l) {
    __builtin_amdgcn_global_load_lds(
        (const __attribute__((address_space(1))) unsigned int*)g,
        (__attribute__((address_space(3))) unsigned int*)l, 16, 0, 0);
}

// ---------------- fused prep: x -> bf16, W1/W2/W3 -> transposed bf16 --------

__global__ __launch_bounds__(256)
void prep_kernel(const float* __restrict__ x, unsigned short* __restrict__ x_bf,
                 const float* __restrict__ W1, unsigned short* __restrict__ W1T,
                 const float* __restrict__ W2, unsigned short* __restrict__ W2T,
                 const float* __restrict__ W3, unsigned short* __restrict__ W3T,
                 int n4) {
    int i = blockIdx.x * 256 + threadIdx.x;
    if (i < n4) {
        float4 v = ((const float4*)x)[i];
        ushort4 o;
        o.x = f2bf(v.x); o.y = f2bf(v.y); o.z = f2bf(v.z); o.w = f2bf(v.w);
        ((ushort4*)x_bf)[i] = o;
        return;
    }
    int j = i - n4;
    if (j < 256 * 512) {                       // W1 [256,512] -> W1T [512,256]
        int k = j >> 9, n = j & 511;
        W1T[(size_t)n * 256 + k] = f2bf(W1[j]);
    } else if ((j -= 256 * 512) < 512 * 512) { // W2 [512,512] -> W2T [512,512]
        int k = j >> 9, n = j & 511;
        W2T[(size_t)n * 512 + k] = f2bf(W2[j]);
    } else if ((j -= 512 * 512) < 512 * 128) { // W3 [512,128] -> W3T [128,512]
        int k = j >> 7, n = j & 127;
        W3T[(size_t)n * 512 + k] = f2bf(W3[j]);
    }
}

// ---------------- CSR build ----------------
// cursor zeroed via hipMemsetAsync; holds EDGE counts only. Self-loops are
// folded in arithmetically: row_ptr[i] = edge_prefix(i) + i  (the "+i" trick).

__global__ __launch_bounds__(256)
void hist_kernel(const int* __restrict__ ei, int* cursor, int E) {
    int e = blockIdx.x * 256 + threadIdx.x;
    if (e < E) atomicAdd(&cursor[ei[E + e]], 1);   // ei[1][e] = dst
}

// parallel scan, step 1: per-1024-block sums
__global__ __launch_bounds__(1024)
void scan_bsum_kernel(const int* __restrict__ cursor, int* __restrict__ bsum, int N) {
    __shared__ int wsum[16];
    int tid = threadIdx.x, lane = tid & 63, w = tid >> 6;
    int i = blockIdx.x * 1024 + tid;
    int v = (i < N) ? cursor[i] : 0;
    #pragma unroll
    for (int off = 32; off; off >>= 1) v += __shfl_xor(v, off, 64);
    if (lane == 0) wsum[w] = v;
    __syncthreads();
    if (tid == 0) {
        int t = 0;
        #pragma unroll
        for (int k = 0; k < 16; ++k) t += wsum[k];
        bsum[blockIdx.x] = t;
    }
}

// step 2: single-wave exclusive scan of <=64 block sums; row_ptr[N] = E + N
__global__ __launch_bounds__(64)
void scan_boffs_kernel(const int* __restrict__ bsum, int* __restrict__ boffs,
                       int NB, int* __restrict__ row_ptr, int N) {
    int lane = threadIdx.x;
    int v = (lane < NB) ? bsum[lane] : 0;
    int x = v;
    #pragma unroll
    for (int off = 1; off < 64; off <<= 1) {
        int t = __shfl_up(x, off, 64);
        if (lane >= off) x += t;
    }
    if (lane < NB) boffs[lane] = x - v;
    if (lane == 63) row_ptr[N] = x + N;  // edges + self-loops
}

// step 3: per-block inclusive scan + block offset + i -> exclusive scan out
__global__ __launch_bounds__(1024)
void scan_final_kernel(int* __restrict__ cursor, const int* __restrict__ boffs,
                       int* __restrict__ row_ptr, int N) {
    __shared__ int wsum[16];
    int tid = threadIdx.x, lane = tid & 63, w = tid >> 6;
    int i = blockIdx.x * 1024 + tid;
    int v = (i < N) ? cursor[i] : 0;
    int x = v;
    #pragma unroll
    for (int off = 1; off < 64; off <<= 1) {
        int t = __shfl_up(x, off, 64);
        if (lane >= off) x += t;
    }
    if (lane == 63) wsum[w] = x;
    __syncthreads();
    if (w == 0 && lane < 16) {
        int y = wsum[lane];
        #pragma unroll
        for (int off = 1; off < 16; off <<= 1) {
            int t = __shfl_up(y, off, 64);
            if (lane >= off) y += t;
        }
        wsum[lane] = y;
    }
    __syncthreads();
    int woff = (w == 0) ? 0 : wsum[w - 1];
    int ex = boffs[blockIdx.x] + woff + x - v + i;   // + i = self-loop slots
    if (i < N) { row_ptr[i] = ex; cursor[i] = ex; }
}

__global__ __launch_bounds__(256)
void scatter_kernel(const int* __restrict__ ei, int* cursor,
                    int* __restrict__ csr_src, int E, int N) {
    int i = blockIdx.x * 256 + threadIdx.x;
    if (i < E) {
        int s = ei[i], d = ei[E + i];
        int pos = atomicAdd(&cursor[d], 1);
        csr_src[pos] = s;
    } else if (i < E + N) {
        int n = i - E;
        int pos = atomicAdd(&cursor[n], 1);
        csr_src[pos] = n;                // self loop
    }
}

// ---------------- bf16 MFMA GEMM + fused attention dots (R6 version) --------
// C[M,Nn]bf16 = A[M,K]bf16 @ BT[Nn,K]^T. 128x128 tile, BK=32, 4 waves.
// LDS staging via global_load_lds (16B/lane), XOR-swizzled (conflict-free).
// NOTE: R7's LDS-free register K-loop regressed (16 cachelines/instr fragment
// gathers + per-wave B re-reads). Keep LDS staging.
// Block x covers one head; epilogue computes a_src/a_dst[row,head].

__global__ __launch_bounds__(256)
void mfma_gemm_kernel(const unsigned short* __restrict__ A,
                      const unsigned short* __restrict__ BT,
                      unsigned short* __restrict__ C,
                      const float* __restrict__ att_src,
                      const float* __restrict__ att_dst,
                      float* __restrict__ a_srcO, float* __restrict__ a_dstO,
                      int H, int M, int Nn, int K) {
    __shared__ unsigned short As[128 * 32];
    __shared__ unsigned short Bs[128 * 32];
    __shared__ float psum[2][128];
    __shared__ float pdsum[2][128];
    const int tid = threadIdx.x;
    const int m0 = blockIdx.y * 128;
    const int n0 = blockIdx.x * 128;
    const int head = blockIdx.x;               // Nn == H*128
    const int lane = tid & 63, wave = tid >> 6;
    const int wm = (wave & 1) * 64, wn = (wave >> 1) * 64;
    const int quad = lane >> 4, rr = lane & 15;

    const int r16 = lane >> 2;
    const int phys = lane & 3;
    const int rowL0 = wave * 32 + r16;
    const int rowL1 = wave * 32 + 16 + r16;
    const int seg0 = phys ^ ((rowL0 >> 1) & 3);
    const int seg1 = phys ^ ((rowL1 >> 1) & 3);
    const int gmA0 = min(m0 + rowL0, M - 1);
    const int gmA1 = min(m0 + rowL1, M - 1);
    const int gnB0 = n0 + rowL0;
    const int gnB1 = n0 + rowL1;
    unsigned short* ldsA0 = As + (wave * 32) * 32;
    unsigned short* ldsA1 = As + (wave * 32 + 16) * 32;
    unsigned short* ldsB0 = Bs + (wave * 32) * 32;
    unsigned short* ldsB1 = Bs + (wave * 32 + 16) * 32;

    const int swz = quad ^ ((rr >> 1) & 3);

    floatx4 acc[4][4] = {};

    for (int k0 = 0; k0 < K; k0 += 32) {
        async_copy16(A  + (size_t)gmA0 * K + k0 + seg0 * 8, ldsA0);
        async_copy16(A  + (size_t)gmA1 * K + k0 + seg1 * 8, ldsA1);
        async_copy16(BT + (size_t)gnB0 * K + k0 + seg0 * 8, ldsB0);
        async_copy16(BT + (size_t)gnB1 * K + k0 + seg1 * 8, ldsB1);
        __syncthreads();

        short8 af[4], bf[4];
        #pragma unroll
        for (int mi = 0; mi < 4; ++mi)
            af[mi] = *(const short8*)(As + (wm + mi * 16 + rr) * 32 + swz * 8);
        #pragma unroll
        for (int ni = 0; ni < 4; ++ni)
            bf[ni] = *(const short8*)(Bs + (wn + ni * 16 + rr) * 32 + swz * 8);
        #pragma unroll
        for (int mi = 0; mi < 4; ++mi)
            #pragma unroll
            for (int ni = 0; ni < 4; ++ni)
                acc[mi][ni] = __builtin_amdgcn_mfma_f32_16x16x32_bf16(
                    af[mi], bf[ni], acc[mi][ni], 0, 0, 0);
        __syncthreads();
    }

    // ---- h store (bf16), C/D layout: col=lane&15, row=quad*4+reg ----
    #pragma unroll
    for (int mi = 0; mi < 4; ++mi) {
        #pragma unroll
        for (int ni = 0; ni < 4; ++ni) {
            int col = n0 + wn + ni * 16 + rr;
            #pragma unroll
            for (int r = 0; r < 4; ++r) {
                int row = m0 + wm + mi * 16 + quad * 4 + r;
                if (row < M) C[(size_t)row * Nn + col] = f2bf(acc[mi][ni][r]);
            }
        }
    }

    // ---- fused attention dots ----
    float ats[4], atd[4];
    #pragma unroll
    for (int ni = 0; ni < 4; ++ni) {
        int c = wn + ni * 16 + rr;          // channel within head
        ats[ni] = att_src[head * 128 + c];
        atd[ni] = att_dst[head * 128 + c];
    }
    const int wnh = wn >> 6;
    #pragma unroll
    for (int mi = 0; mi < 4; ++mi) {
        #pragma unroll
        for (int r = 0; r < 4; ++r) {
            float ps = 0.f, pd = 0.f;
            #pragma unroll
            for (int ni = 0; ni < 4; ++ni) {
                ps += ats[ni] * acc[mi][ni][r];
                pd += atd[ni] * acc[mi][ni][r];
            }
            #pragma unroll
            for (int off = 1; off < 16; off <<= 1) {
                ps += __shfl_xor(ps, off, 64);
                pd += __shfl_xor(pd, off, 64);
            }
            if (rr == 0) {
                int row = wm + mi * 16 + quad * 4 + r;   // local row
                psum[wnh][row] = ps;
                pdsum[wnh][row] = pd;
            }
        }
    }
    __syncthreads();
    if (tid < 128) {
        int gr = m0 + tid;
        if (gr < M) {
            a_srcO[(size_t)gr * H + head] = psum[0][tid] + psum[1][tid];
            a_dstO[(size_t)gr * H + head] = pdsum[0][tid] + pdsum[1][tid];
        }
    }
}

// ---------------- per-dst-node softmax + aggregation (R6 version) -----------
// One WAVE per dst node. Single pass: exp(e) without max subtraction (logits
// O(1): identical ratio, fp32-safe). Depth-4 pipelined row gathers (16B/lane);
// scalarized CSR chain. No LDS/barriers. This is the best-known agg:
// R6 depth-4 = neutral vs depth-2; R8 head-slice cut FETCH but regressed.

template<int F, int H, bool RELU, bool BF16OUT>
__global__ __launch_bounds__(256)
void agg_kernel(const unsigned* __restrict__ hfeat, const float* __restrict__ a_src,
                const float* __restrict__ a_dst, const int* __restrict__ row_ptr,
                const int* __restrict__ csr_src, const float* __restrict__ bias,
                void* __restrict__ out_v, int N) {
    constexpr int UPL = F / 128;             // uints per lane: 4 or 1
    constexpr int RU = F / 2;                // uints per row
    const int wave = threadIdx.x >> 6, lane = threadIdx.x & 63;
    const int n = blockIdx.x * 4 + wave;
    if (n >= N) return;
    const int begin = __builtin_amdgcn_readfirstlane(row_ptr[n]);
    const int deg = __builtin_amdgcn_readfirstlane(row_ptr[n + 1]) - begin;
    const int myh = (2 * UPL * lane) / 128;
    const float adst = a_dst[n * H + myh];

    float acc[2 * UPL];
    #pragma unroll
    for (int j = 0; j < 2 * UPL; ++j) acc[j] = 0.f;
    float dacc = 0.f;

    unsigned u0[UPL], u1[UPL], u2[UPL], u3[UPL];
    float av0 = 0.f, av1 = 0.f, av2 = 0.f, av3 = 0.f;

#define LOADSLOT(idx, U, AV)                                              \
    {                                                                     \
        int s_ = __builtin_amdgcn_readfirstlane(csr_src[begin + (idx)]);  \
        if (UPL == 4) {                                                   \
            uint4 t_ = ((const uint4*)(hfeat + (size_t)s_ * RU))[lane];   \
            U[0] = t_.x; U[1] = t_.y; U[2] = t_.z; U[3] = t_.w;           \
        } else {                                                          \
            U[0] = hfeat[(size_t)s_ * RU + lane];                         \
        }                                                                 \
        AV = a_src[s_ * H + myh];                                         \
    }

#define CONSUME(U, AV)                                                    \
    {                                                                     \
        float e_ = AV + adst;                                             \
        e_ = e_ > 0.f ? e_ : NEG_SLOPE * e_;                              \
        float ex_ = __expf(e_);                                           \
        dacc += ex_;                                                      \
        _Pragma("unroll")                                                 \
        for (int q_ = 0; q_ < UPL; ++q_) {                                \
            acc[2 * q_]     += ex_ * bf2f_lo(U[q_]);                      \
            acc[2 * q_ + 1] += ex_ * bf2f_hi(U[q_]);                      \
        }                                                                 \
    }

    LOADSLOT(0, u0, av0);
    if (deg > 1) LOADSLOT(1, u1, av1);
    if (deg > 2) LOADSLOT(2, u2, av2);
    if (deg > 3) LOADSLOT(3, u3, av3);
    int i = 0;
    for (; i + 8 <= deg; i += 4) {
        CONSUME(u0, av0); LOADSLOT(i + 4, u0, av0);
        CONSUME(u1, av1); LOADSLOT(i + 5, u1, av1);
        CONSUME(u2, av2); LOADSLOT(i + 6, u2, av2);
        CONSUME(u3, av3); LOADSLOT(i + 7, u3, av3);
    }
    int rem = deg - i;                       // 1..7
    CONSUME(u0, av0); if (rem > 4) LOADSLOT(i + 4, u0, av0);
    if (rem > 1) { CONSUME(u1, av1); if (rem > 5) LOADSLOT(i + 5, u1, av1); }
    if (rem > 2) { CONSUME(u2, av2); if (rem > 6) LOADSLOT(i + 6, u2, av2); }
    if (rem > 3) CONSUME(u3, av3);
    if (rem > 4) CONSUME(u0, av0);
    if (rem > 5) CONSUME(u1, av1);
    if (rem > 6) CONSUME(u2, av2);
#undef LOADSLOT
#undef CONSUME

    float inv = 1.f / dacc;
    const int cb = 2 * UPL * lane;
    if (BF16OUT) {
        unsigned pk[UPL];
        #pragma unroll
        for (int q = 0; q < UPL; ++q) {
            float v0 = acc[2 * q] * inv + bias[cb + 2 * q];
            float v1 = acc[2 * q + 1] * inv + bias[cb + 2 * q + 1];
            if (RELU) { v0 = fmaxf(v0, 0.f); v1 = fmaxf(v1, 0.f); }
            pk[q] = (unsigned)f2bf(v0) | ((unsigned)f2bf(v1) << 16);
        }
        if (UPL == 4) {
            uint4 t; t.x = pk[0]; t.y = pk[1]; t.z = pk[2]; t.w = pk[3];
            ((uint4*)((unsigned*)out_v + (size_t)n * RU))[lane] = t;
        } else {
            ((unsigned*)out_v)[(size_t)n * RU + lane] = pk[0];
        }
    } else {
        #pragma unroll
        for (int q = 0; q < UPL; ++q) {
            float v0 = acc[2 * q] * inv + bias[cb + 2 * q];
            float v1 = acc[2 * q + 1] * inv + bias[cb + 2 * q + 1];
            if (RELU) { v0 = fmaxf(v0, 0.f); v1 = fmaxf(v1, 0.f); }
            float2 o; o.x = v0; o.y = v1;
            ((float2*)((float*)out_v + (size_t)n * F))[UPL * lane + q] = o;
        }
    }
}

// ---------------- host launch ----------------

extern "C" void kernel_launch(void* const* d_in, const int* in_sizes, int n_in,
                              void* d_out, int out_size, void* d_ws, size_t ws_size,
                              hipStream_t stream) {
    const float* x        = (const float*)d_in[0];
    const int*   ei       = (const int*)  d_in[1];
    const float* W1       = (const float*)d_in[2];
    const float* att_src1 = (const float*)d_in[3];
    const float* att_dst1 = (const float*)d_in[4];
    const float* b1       = (const float*)d_in[5];
    const float* W2       = (const float*)d_in[6];
    const float* att_src2 = (const float*)d_in[7];
    const float* att_dst2 = (const float*)d_in[8];
    const float* b2       = (const float*)d_in[9];
    const float* W3       = (const float*)d_in[10];
    const float* att_src3 = (const float*)d_in[11];
    const float* att_dst3 = (const float*)d_in[12];
    const float* b3       = (const float*)d_in[13];

    const int IN_FEATS = 256;
    const int N = in_sizes[0] / IN_FEATS;   // 30000
    const int E = in_sizes[1] / 2;          // 480000
    const int ET = E + N;
    const int NB = (N + 1023) / 1024;       // scan blocks (30)

    // workspace layout
    char* p = (char*)d_ws;
    unsigned short* h_bf    = (unsigned short*)p; p += (size_t)N * 512 * sizeof(unsigned short);
    unsigned short* act_bf  = (unsigned short*)p; p += (size_t)N * 512 * sizeof(unsigned short);
    unsigned short* x_bf    = (unsigned short*)p; p += (size_t)N * 256 * sizeof(unsigned short);
    float*          a_src   = (float*)p;          p += (size_t)N * 4 * sizeof(float);
    float*          a_dst   = (float*)p;          p += (size_t)N * 4 * sizeof(float);
    unsigned short* W1T     = (unsigned short*)p; p += (size_t)512 * 256 * sizeof(unsigned short);
    unsigned short* W2T     = (unsigned short*)p; p += (size_t)512 * 512 * sizeof(unsigned short);
    unsigned short* W3T     = (unsigned short*)p; p += (size_t)128 * 512 * sizeof(unsigned short);
    int*            row_ptr = (int*)p;            p += ((size_t)N + 16) * sizeof(int);
    int*            cursor  = (int*)p;            p += ((size_t)N + 16) * sizeof(int);
    int*            bsum    = (int*)p;            p += 64 * sizeof(int);
    int*            boffs   = (int*)p;            p += 64 * sizeof(int);
    int*            csr_src = (int*)p;            p += (size_t)ET * sizeof(int);

    // ---- prep (x cast + all W transposes) + CSR build ----
    hipMemsetAsync(cursor, 0, (size_t)N * sizeof(int), stream);
    {
        int n4 = N * 256 / 4;
        int total = n4 + 256 * 512 + 512 * 512 + 512 * 128;
        prep_kernel<<<(total + 255) / 256, 256, 0, stream>>>(
            x, x_bf, W1, W1T, W2, W2T, W3, W3T, n4);
    }
    hist_kernel<<<(E + 255) / 256, 256, 0, stream>>>(ei, cursor, E);
    scan_bsum_kernel<<<NB, 1024, 0, stream>>>(cursor, bsum, N);
    scan_boffs_kernel<<<1, 64, 0, stream>>>(bsum, boffs, NB, row_ptr, N);
    scan_final_kernel<<<NB, 1024, 0, stream>>>(cursor, boffs, row_ptr, N);
    scatter_kernel<<<(E + N + 255) / 256, 256, 0, stream>>>(ei, cursor, csr_src, E, N);

    const int MB = (N + 127) / 128;
    const int NB4 = (N + 3) / 4;

    // ---- Layer 1: 256 -> 4x128 concat + relu (h bf16) ----
    mfma_gemm_kernel<<<dim3(4, MB), 256, 0, stream>>>(x_bf, W1T, h_bf, att_src1, att_dst1, a_src, a_dst, 4, N, 512, 256);
    agg_kernel<512, 4, true, true><<<NB4, 256, 0, stream>>>((const unsigned*)h_bf, a_src, a_dst, row_ptr, csr_src, b1, act_bf, N);

    // ---- Layer 2: 512 -> 4x128 concat + relu (h bf16) ----
    mfma_gemm_kernel<<<dim3(4, MB), 256, 0, stream>>>(act_bf, W2T, h_bf, att_src2, att_dst2, a_src, a_dst, 4, N, 512, 512);
    agg_kernel<512, 4, true, true><<<NB4, 256, 0, stream>>>((const unsigned*)h_bf, a_src, a_dst, row_ptr, csr_src, b2, act_bf, N);

    // ---- Layer 3: 512 -> 1x128 (h bf16), fp32 out, no relu ----
    mfma_gemm_kernel<<<dim3(1, MB), 256, 0, stream>>>(act_bf, W3T, h_bf, att_src3, att_dst3, a_src, a_dst, 1, N, 128, 512);
    agg_kernel<128, 1, false, false><<<NB4, 256, 0, stream>>>((const unsigned*)h_bf, a_src, a_dst, row_ptr, csr_src, b3, d_out, N);
}

// Round 10
// 408.813 us; speedup vs baseline: 1.1392x; 1.0170x over previous
//
#include <hip/hip_runtime.h>

// ---------------------------------------------------------------------------
// DistributionShiftGAT: 3-layer GAT on MI355X (gfx950).
// R10: GEMM K-tile BK=32 -> BK=64 (halves s_barrier/vmcnt(0) drains; short-K
//      GEMMs never amortized them). Dispatch merges: scan_boffs folded into
//      scan_final (per-block redundant 30-elem scan); prep+hist one kernel.
//      11 dispatches total. Agg = R6 wave-per-node (proven floor ~75us:
//      depth-4 neutral, R8 head-slice regressed). R7 LDS-free GEMM regressed.
// ---------------------------------------------------------------------------

#define NEG_SLOPE 0.2f

typedef __attribute__((ext_vector_type(8))) short short8;
typedef __attribute__((ext_vector_type(4))) float floatx4;

static __device__ __forceinline__ unsigned short f2bf(float f) {
    unsigned u = __float_as_uint(f);
    u = u + 0x7FFFu + ((u >> 16) & 1u);      // RNE
    return (unsigned short)(u >> 16);
}
static __device__ __forceinline__ float bf2f_lo(unsigned u) {
    return __uint_as_float(u << 16);
}
static __device__ __forceinline__ float bf2f_hi(unsigned u) {
    return __uint_as_float(u & 0xFFFF0000u);
}

// async global->LDS, 16B per lane; LDS fills base + lane*16 (wave-uniform base)
static __device__ __forceinline__ void async_copy16(const void* g, void* l) {
    __builtin_amdgcn_global_load_lds(
        (const __attribute__((address_space(1))) unsigned int*)g,
        (__attribute__((address_space(3))) unsigned int*)l, 16, 0, 0);
}

// ---------------- fused prep (x cast + W transposes) + edge histogram -------
// cursor must be zeroed (hipMemsetAsync) before this kernel.

__global__ __launch_bounds__(256)
void prep_hist_kernel(const float* __restrict__ x, unsigned short* __restrict__ x_bf,
                      const float* __restrict__ W1, unsigned short* __restrict__ W1T,
                      const float* __restrict__ W2, unsigned short* __restrict__ W2T,
                      const float* __restrict__ W3, unsigned short* __restrict__ W3T,
                      const int* __restrict__ ei, int* cursor, int n4, int E) {
    int i = blockIdx.x * 256 + threadIdx.x;
    if (i < n4) {
        float4 v = ((const float4*)x)[i];
        ushort4 o;
        o.x = f2bf(v.x); o.y = f2bf(v.y); o.z = f2bf(v.z); o.w = f2bf(v.w);
        ((ushort4*)x_bf)[i] = o;
        return;
    }
    int j = i - n4;
    if (j < 256 * 512) {                       // W1 [256,512] -> W1T [512,256]
        int k = j >> 9, n = j & 511;
        W1T[(size_t)n * 256 + k] = f2bf(W1[j]);
        return;
    }
    j -= 256 * 512;
    if (j < 512 * 512) {                       // W2 [512,512] -> W2T [512,512]
        int k = j >> 9, n = j & 511;
        W2T[(size_t)n * 512 + k] = f2bf(W2[j]);
        return;
    }
    j -= 512 * 512;
    if (j < 512 * 128) {                       // W3 [512,128] -> W3T [128,512]
        int k = j >> 7, n = j & 127;
        W3T[(size_t)n * 512 + k] = f2bf(W3[j]);
        return;
    }
    j -= 512 * 128;
    if (j < E) atomicAdd(&cursor[ei[E + j]], 1);   // histogram of dst
}

// ---------------- CSR scan ----------------
// Self-loops folded arithmetically: row_ptr[i] = edge_prefix(i) + i.

// step 1: per-1024-block sums
__global__ __launch_bounds__(1024)
void scan_bsum_kernel(const int* __restrict__ cursor, int* __restrict__ bsum, int N) {
    __shared__ int wsum[16];
    int tid = threadIdx.x, lane = tid & 63, w = tid >> 6;
    int i = blockIdx.x * 1024 + tid;
    int v = (i < N) ? cursor[i] : 0;
    #pragma unroll
    for (int off = 32; off; off >>= 1) v += __shfl_xor(v, off, 64);
    if (lane == 0) wsum[w] = v;
    __syncthreads();
    if (tid == 0) {
        int t = 0;
        #pragma unroll
        for (int k = 0; k < 16; ++k) t += wsum[k];
        bsum[blockIdx.x] = t;
    }
}

// step 2: per-block scan; wave 0 also redoes the tiny NB-element block-offset
// scan (NB<=64) so no separate boffs kernel/dispatch is needed.
__global__ __launch_bounds__(1024)
void scan_final_kernel(int* __restrict__ cursor, const int* __restrict__ bsum,
                       int* __restrict__ row_ptr, int N, int NB) {
    __shared__ int wsum[16];
    __shared__ int boff_sh;
    int tid = threadIdx.x, lane = tid & 63, w = tid >> 6;
    if (w == 0) {
        int bv = (lane < NB) ? bsum[lane] : 0;
        int bx = bv;
        #pragma unroll
        for (int off = 1; off < 64; off <<= 1) {
            int t = __shfl_up(bx, off, 64);
            if (lane >= off) bx += t;
        }
        if (lane == blockIdx.x) boff_sh = bx - bv;       // exclusive prefix
        if (blockIdx.x == 0 && lane == 63) row_ptr[N] = bx + N;  // +N self-loops
    }
    int i = blockIdx.x * 1024 + tid;
    int v = (i < N) ? cursor[i] : 0;
    int x = v;
    #pragma unroll
    for (int off = 1; off < 64; off <<= 1) {
        int t = __shfl_up(x, off, 64);
        if (lane >= off) x += t;
    }
    if (lane == 63) wsum[w] = x;
    __syncthreads();
    if (w == 0 && lane < 16) {
        int y = wsum[lane];
        #pragma unroll
        for (int off = 1; off < 16; off <<= 1) {
            int t = __shfl_up(y, off, 64);
            if (lane >= off) y += t;
        }
        wsum[lane] = y;
    }
    __syncthreads();
    int woff = (w == 0) ? 0 : wsum[w - 1];
    int ex = boff_sh + woff + x - v + i;     // + i = self-loop slots
    if (i < N) { row_ptr[i] = ex; cursor[i] = ex; }
}

__global__ __launch_bounds__(256)
void scatter_kernel(const int* __restrict__ ei, int* cursor,
                    int* __restrict__ csr_src, int E, int N) {
    int i = blockIdx.x * 256 + threadIdx.x;
    if (i < E) {
        int s = ei[i], d = ei[E + i];
        int pos = atomicAdd(&cursor[d], 1);
        csr_src[pos] = s;
    } else if (i < E + N) {
        int n = i - E;
        int pos = atomicAdd(&cursor[n], 1);
        csr_src[pos] = n;                // self loop
    }
}

// ---------------- bf16 MFMA GEMM + fused attention dots ----------------
// C[M,Nn]bf16 = A[M,K]bf16 @ BT[Nn,K]^T. 128x128 tile, BK=64, 4 waves.
// LDS staging via global_load_lds (16B/lane). 64-elem rows: phys seg =
// logical seg ^ (row&7) -> each b128 frag read spreads 256 words evenly over
// 32 banks (8/bank = minimum). BK=64 halves barrier drains vs BK=32 (short-K
// GEMMs are drain-dominated). R7's LDS-free variant regressed (16 cachelines
// per fragment load + per-wave B re-reads) -- keep LDS staging.
// Block x covers one head; epilogue computes a_src/a_dst[row,head].

__global__ __launch_bounds__(256)
void mfma_gemm_kernel(const unsigned short* __restrict__ A,
                      const unsigned short* __restrict__ BT,
                      unsigned short* __restrict__ C,
                      const float* __restrict__ att_src,
                      const float* __restrict__ att_dst,
                      float* __restrict__ a_srcO, float* __restrict__ a_dstO,
                      int H, int M, int Nn, int K) {
    __shared__ unsigned short As[128 * 64];   // 16 KB
    __shared__ unsigned short Bs[128 * 64];   // 16 KB
    __shared__ float psum[2][128];
    __shared__ float pdsum[2][128];
    const int tid = threadIdx.x;
    const int m0 = blockIdx.y * 128;
    const int n0 = blockIdx.x * 128;
    const int head = blockIdx.x;               // Nn == H*128
    const int lane = tid & 63, wave = tid >> 6;
    const int wm = (wave & 1) * 64, wn = (wave >> 1) * 64;
    const int quad = lane >> 4, rr = lane & 15;

    // staging: 64 lanes x 16B = 8 rows/inst; 4 insts cover 32 rows per wave.
    const int srow = lane >> 3;                // 0..7: row within 8-row group
    const int sseg = (lane & 7) ^ srow;        // logical 8-elem seg to fetch
    int gArow[4], gBrow[4];
    #pragma unroll
    for (int j = 0; j < 4; ++j) {
        int rowL = wave * 32 + j * 8 + srow;
        gArow[j] = min(m0 + rowL, M - 1);
        gBrow[j] = n0 + rowL;
    }

    floatx4 acc[4][4] = {};

    for (int k0 = 0; k0 < K; k0 += 64) {
        #pragma unroll
        for (int j = 0; j < 4; ++j) {
            async_copy16(A  + (size_t)gArow[j] * K + k0 + sseg * 8,
                         As + (wave * 32 + j * 8) * 64);
            async_copy16(BT + (size_t)gBrow[j] * K + k0 + sseg * 8,
                         Bs + (wave * 32 + j * 8) * 64);
        }
        __syncthreads();

        #pragma unroll
        for (int k32 = 0; k32 < 2; ++k32) {
            short8 af[4], bf[4];
            #pragma unroll
            for (int mi = 0; mi < 4; ++mi) {
                int row = wm + mi * 16 + rr;
                int phys = (k32 * 4 + quad) ^ (rr & 7);
                af[mi] = *(const short8*)(As + row * 64 + phys * 8);
            }
            #pragma unroll
            for (int ni = 0; ni < 4; ++ni) {
                int row = wn + ni * 16 + rr;
                int phys = (k32 * 4 + quad) ^ (rr & 7);
                bf[ni] = *(const short8*)(Bs + row * 64 + phys * 8);
            }
            #pragma unroll
            for (int mi = 0; mi < 4; ++mi)
                #pragma unroll
                for (int ni = 0; ni < 4; ++ni)
                    acc[mi][ni] = __builtin_amdgcn_mfma_f32_16x16x32_bf16(
                        af[mi], bf[ni], acc[mi][ni], 0, 0, 0);
        }
        __syncthreads();
    }

    // ---- h store (bf16), C/D layout: col=lane&15, row=quad*4+reg ----
    #pragma unroll
    for (int mi = 0; mi < 4; ++mi) {
        #pragma unroll
        for (int ni = 0; ni < 4; ++ni) {
            int col = n0 + wn + ni * 16 + rr;
            #pragma unroll
            for (int r = 0; r < 4; ++r) {
                int row = m0 + wm + mi * 16 + quad * 4 + r;
                if (row < M) C[(size_t)row * Nn + col] = f2bf(acc[mi][ni][r]);
            }
        }
    }

    // ---- fused attention dots ----
    float ats[4], atd[4];
    #pragma unroll
    for (int ni = 0; ni < 4; ++ni) {
        int c = wn + ni * 16 + rr;          // channel within head
        ats[ni] = att_src[head * 128 + c];
        atd[ni] = att_dst[head * 128 + c];
    }
    const int wnh = wn >> 6;
    #pragma unroll
    for (int mi = 0; mi < 4; ++mi) {
        #pragma unroll
        for (int r = 0; r < 4; ++r) {
            float ps = 0.f, pd = 0.f;
            #pragma unroll
            for (int ni = 0; ni < 4; ++ni) {
                ps += ats[ni] * acc[mi][ni][r];
                pd += atd[ni] * acc[mi][ni][r];
            }
            #pragma unroll
            for (int off = 1; off < 16; off <<= 1) {
                ps += __shfl_xor(ps, off, 64);
                pd += __shfl_xor(pd, off, 64);
            }
            if (rr == 0) {
                int row = wm + mi * 16 + quad * 4 + r;   // local row
                psum[wnh][row] = ps;
                pdsum[wnh][row] = pd;
            }
        }
    }
    __syncthreads();
    if (tid < 128) {
        int gr = m0 + tid;
        if (gr < M) {
            a_srcO[(size_t)gr * H + head] = psum[0][tid] + psum[1][tid];
            a_dstO[(size_t)gr * H + head] = pdsum[0][tid] + pdsum[1][tid];
        }
    }
}

// ---------------- per-dst-node softmax + aggregation (R6 version) -----------
// One WAVE per dst node. Single pass: exp(e) without max subtraction (logits
// O(1): identical ratio, fp32-safe). Depth-4 pipelined row gathers (16B/lane);
// scalarized CSR chain. No LDS/barriers. Proven floor ~75us: depth-4 neutral
// vs depth-2 (R6), head-slice cut FETCH but regressed (R8).

template<int F, int H, bool RELU, bool BF16OUT>
__global__ __launch_bounds__(256)
void agg_kernel(const unsigned* __restrict__ hfeat, const float* __restrict__ a_src,
                const float* __restrict__ a_dst, const int* __restrict__ row_ptr,
                const int* __restrict__ csr_src, const float* __restrict__ bias,
                void* __restrict__ out_v, int N) {
    constexpr int UPL = F / 128;             // uints per lane: 4 or 1
    constexpr int RU = F / 2;                // uints per row
    const int wave = threadIdx.x >> 6, lane = threadIdx.x & 63;
    const int n = blockIdx.x * 4 + wave;
    if (n >= N) return;
    const int begin = __builtin_amdgcn_readfirstlane(row_ptr[n]);
    const int deg = __builtin_amdgcn_readfirstlane(row_ptr[n + 1]) - begin;
    const int myh = (2 * UPL * lane) / 128;
    const float adst = a_dst[n * H + myh];

    float acc[2 * UPL];
    #pragma unroll
    for (int j = 0; j < 2 * UPL; ++j) acc[j] = 0.f;
    float dacc = 0.f;

    unsigned u0[UPL], u1[UPL], u2[UPL], u3[UPL];
    float av0 = 0.f, av1 = 0.f, av2 = 0.f, av3 = 0.f;

#define LOADSLOT(idx, U, AV)                                              \
    {                                                                     \
        int s_ = __builtin_amdgcn_readfirstlane(csr_src[begin + (idx)]);  \
        if (UPL == 4) {                                                   \
            uint4 t_ = ((const uint4*)(hfeat + (size_t)s_ * RU))[lane];   \
            U[0] = t_.x; U[1] = t_.y; U[2] = t_.z; U[3] = t_.w;           \
        } else {                                                          \
            U[0] = hfeat[(size_t)s_ * RU + lane];                         \
        }                                                                 \
        AV = a_src[s_ * H + myh];                                         \
    }

#define CONSUME(U, AV)                                                    \
    {                                                                     \
        float e_ = AV + adst;                                             \
        e_ = e_ > 0.f ? e_ : NEG_SLOPE * e_;                              \
        float ex_ = __expf(e_);                                           \
        dacc += ex_;                                                      \
        _Pragma("unroll")                                                 \
        for (int q_ = 0; q_ < UPL; ++q_) {                                \
            acc[2 * q_]     += ex_ * bf2f_lo(U[q_]);                      \
            acc[2 * q_ + 1] += ex_ * bf2f_hi(U[q_]);                      \
        }                                                                 \
    }

    LOADSLOT(0, u0, av0);
    if (deg > 1) LOADSLOT(1, u1, av1);
    if (deg > 2) LOADSLOT(2, u2, av2);
    if (deg > 3) LOADSLOT(3, u3, av3);
    int i = 0;
    for (; i + 8 <= deg; i += 4) {
        CONSUME(u0, av0); LOADSLOT(i + 4, u0, av0);
        CONSUME(u1, av1); LOADSLOT(i + 5, u1, av1);
        CONSUME(u2, av2); LOADSLOT(i + 6, u2, av2);
        CONSUME(u3, av3); LOADSLOT(i + 7, u3, av3);
    }
    int rem = deg - i;                       // 1..7
    CONSUME(u0, av0); if (rem > 4) LOADSLOT(i + 4, u0, av0);
    if (rem > 1) { CONSUME(u1, av1); if (rem > 5) LOADSLOT(i + 5, u1, av1); }
    if (rem > 2) { CONSUME(u2, av2); if (rem > 6) LOADSLOT(i + 6, u2, av2); }
    if (rem > 3) CONSUME(u3, av3);
    if (rem > 4) CONSUME(u0, av0);
    if (rem > 5) CONSUME(u1, av1);
    if (rem > 6) CONSUME(u2, av2);
#undef LOADSLOT
#undef CONSUME

    float inv = 1.f / dacc;
    const int cb = 2 * UPL * lane;
    if (BF16OUT) {
        unsigned pk[UPL];
        #pragma unroll
        for (int q = 0; q < UPL; ++q) {
            float v0 = acc[2 * q] * inv + bias[cb + 2 * q];
            float v1 = acc[2 * q + 1] * inv + bias[cb + 2 * q + 1];
            if (RELU) { v0 = fmaxf(v0, 0.f); v1 = fmaxf(v1, 0.f); }
            pk[q] = (unsigned)f2bf(v0) | ((unsigned)f2bf(v1) << 16);
        }
        if (UPL == 4) {
            uint4 t; t.x = pk[0]; t.y = pk[1]; t.z = pk[2]; t.w = pk[3];
            ((uint4*)((unsigned*)out_v + (size_t)n * RU))[lane] = t;
        } else {
            ((unsigned*)out_v)[(size_t)n * RU + lane] = pk[0];
        }
    } else {
        #pragma unroll
        for (int q = 0; q < UPL; ++q) {
            float v0 = acc[2 * q] * inv + bias[cb + 2 * q];
            float v1 = acc[2 * q + 1] * inv + bias[cb + 2 * q + 1];
            if (RELU) { v0 = fmaxf(v0, 0.f); v1 = fmaxf(v1, 0.f); }
            float2 o; o.x = v0; o.y = v1;
            ((float2*)((float*)out_v + (size_t)n * F))[UPL * lane + q] = o;
        }
    }
}

// ---------------- host launch ----------------

extern "C" void kernel_launch(void* const* d_in, const int* in_sizes, int n_in,
                              void* d_out, int out_size, void* d_ws, size_t ws_size,
                              hipStream_t stream) {
    const float* x        = (const float*)d_in[0];
    const int*   ei       = (const int*)  d_in[1];
    const float* W1       = (const float*)d_in[2];
    const float* att_src1 = (const float*)d_in[3];
    const float* att_dst1 = (const float*)d_in[4];
    const float* b1       = (const float*)d_in[5];
    const float* W2       = (const float*)d_in[6];
    const float* att_src2 = (const float*)d_in[7];
    const float* att_dst2 = (const float*)d_in[8];
    const float* b2       = (const float*)d_in[9];
    const float* W3       = (const float*)d_in[10];
    const float* att_src3 = (const float*)d_in[11];
    const float* att_dst3 = (const float*)d_in[12];
    const float* b3       = (const float*)d_in[13];

    const int IN_FEATS = 256;
    const int N = in_sizes[0] / IN_FEATS;   // 30000
    const int E = in_sizes[1] / 2;          // 480000
    const int ET = E + N;
    const int NB = (N + 1023) / 1024;       // scan blocks (30)

    // workspace layout
    char* p = (char*)d_ws;
    unsigned short* h_bf    = (unsigned short*)p; p += (size_t)N * 512 * sizeof(unsigned short);
    unsigned short* act_bf  = (unsigned short*)p; p += (size_t)N * 512 * sizeof(unsigned short);
    unsigned short* x_bf    = (unsigned short*)p; p += (size_t)N * 256 * sizeof(unsigned short);
    float*          a_src   = (float*)p;          p += (size_t)N * 4 * sizeof(float);
    float*          a_dst   = (float*)p;          p += (size_t)N * 4 * sizeof(float);
    unsigned short* W1T     = (unsigned short*)p; p += (size_t)512 * 256 * sizeof(unsigned short);
    unsigned short* W2T     = (unsigned short*)p; p += (size_t)512 * 512 * sizeof(unsigned short);
    unsigned short* W3T     = (unsigned short*)p; p += (size_t)128 * 512 * sizeof(unsigned short);
    int*            row_ptr = (int*)p;            p += ((size_t)N + 16) * sizeof(int);
    int*            cursor  = (int*)p;            p += ((size_t)N + 16) * sizeof(int);
    int*            bsum    = (int*)p;            p += 64 * sizeof(int);
    int*            csr_src = (int*)p;            p += (size_t)ET * sizeof(int);

    // ---- prep (x cast + W transposes + hist) + CSR build ----
    hipMemsetAsync(cursor, 0, (size_t)N * sizeof(int), stream);
    {
        int n4 = N * 256 / 4;
        int total = n4 + 256 * 512 + 512 * 512 + 512 * 128 + E;
        prep_hist_kernel<<<(total + 255) / 256, 256, 0, stream>>>(
            x, x_bf, W1, W1T, W2, W2T, W3, W3T, ei, cursor, n4, E);
    }
    scan_bsum_kernel<<<NB, 1024, 0, stream>>>(cursor, bsum, N);
    scan_final_kernel<<<NB, 1024, 0, stream>>>(cursor, bsum, row_ptr, N, NB);
    scatter_kernel<<<(E + N + 255) / 256, 256, 0, stream>>>(ei, cursor, csr_src, E, N);

    const int MB = (N + 127) / 128;
    const int NB4 = (N + 3) / 4;

    // ---- Layer 1: 256 -> 4x128 concat + relu (h bf16) ----
    mfma_gemm_kernel<<<dim3(4, MB), 256, 0, stream>>>(x_bf, W1T, h_bf, att_src1, att_dst1, a_src, a_dst, 4, N, 512, 256);
    agg_kernel<512, 4, true, true><<<NB4, 256, 0, stream>>>((const unsigned*)h_bf, a_src, a_dst, row_ptr, csr_src, b1, act_bf, N);

    // ---- Layer 2: 512 -> 4x128 concat + relu (h bf16) ----
    mfma_gemm_kernel<<<dim3(4, MB), 256, 0, stream>>>(act_bf, W2T, h_bf, att_src2, att_dst2, a_src, a_dst, 4, N, 512, 512);
    agg_kernel<512, 4, true, true><<<NB4, 256, 0, stream>>>((const unsigned*)h_bf, a_src, a_dst, row_ptr, csr_src, b2, act_bf, N);

    // ---- Layer 3: 512 -> 1x128 (h bf16), fp32 out, no relu ----
    mfma_gemm_kernel<<<dim3(1, MB), 256, 0, stream>>>(act_bf, W3T, h_bf, att_src3, att_dst3, a_src, a_dst, 1, N, 128, 512);
    agg_kernel<128, 1, false, false><<<NB4, 256, 0, stream>>>((const unsigned*)h_bf, a_src, a_dst, row_ptr, csr_src, b3, d_out, N);
}

// Round 11
// 388.918 us; speedup vs baseline: 1.1975x; 1.0512x over previous
//
#include <hip/hip_runtime.h>

// ---------------------------------------------------------------------------
// DistributionShiftGAT: 3-layer GAT on MI355X (gfx950).
// R11: GEMM tiles widened for panel reuse: 128x256 (8 waves/512 thr) for
//      layers 1-2 (B staged once per 2 heads), 256x128 for layer 3. Same
//      64x64 wave tiles, same swizzled global_load_lds staging, A+B in one
//      48KB LDS buffer. Everything else = R10 (proven local optima: agg
//      wave-per-node ~75us pattern wall, 11 dispatches).
// ---------------------------------------------------------------------------

#define NEG_SLOPE 0.2f

typedef __attribute__((ext_vector_type(8))) short short8;
typedef __attribute__((ext_vector_type(4))) float floatx4;

static __device__ __forceinline__ unsigned short f2bf(float f) {
    unsigned u = __float_as_uint(f);
    u = u + 0x7FFFu + ((u >> 16) & 1u);      // RNE
    return (unsigned short)(u >> 16);
}
static __device__ __forceinline__ float bf2f_lo(unsigned u) {
    return __uint_as_float(u << 16);
}
static __device__ __forceinline__ float bf2f_hi(unsigned u) {
    return __uint_as_float(u & 0xFFFF0000u);
}

// async global->LDS, 16B per lane; LDS fills base + lane*16 (wave-uniform base)
static __device__ __forceinline__ void async_copy16(const void* g, void* l) {
    __builtin_amdgcn_global_load_lds(
        (const __attribute__((address_space(1))) unsigned int*)g,
        (__attribute__((address_space(3))) unsigned int*)l, 16, 0, 0);
}

// ---------------- fused prep (x cast + W transposes) + edge histogram -------
// cursor must be zeroed (hipMemsetAsync) before this kernel.

__global__ __launch_bounds__(256)
void prep_hist_kernel(const float* __restrict__ x, unsigned short* __restrict__ x_bf,
                      const float* __restrict__ W1, unsigned short* __restrict__ W1T,
                      const float* __restrict__ W2, unsigned short* __restrict__ W2T,
                      const float* __restrict__ W3, unsigned short* __restrict__ W3T,
                      const int* __restrict__ ei, int* cursor, int n4, int E) {
    int i = blockIdx.x * 256 + threadIdx.x;
    if (i < n4) {
        float4 v = ((const float4*)x)[i];
        ushort4 o;
        o.x = f2bf(v.x); o.y = f2bf(v.y); o.z = f2bf(v.z); o.w = f2bf(v.w);
        ((ushort4*)x_bf)[i] = o;
        return;
    }
    int j = i - n4;
    if (j < 256 * 512) {                       // W1 [256,512] -> W1T [512,256]
        int k = j >> 9, n = j & 511;
        W1T[(size_t)n * 256 + k] = f2bf(W1[j]);
        return;
    }
    j -= 256 * 512;
    if (j < 512 * 512) {                       // W2 [512,512] -> W2T [512,512]
        int k = j >> 9, n = j & 511;
        W2T[(size_t)n * 512 + k] = f2bf(W2[j]);
        return;
    }
    j -= 512 * 512;
    if (j < 512 * 128) {                       // W3 [512,128] -> W3T [128,512]
        int k = j >> 7, n = j & 127;
        W3T[(size_t)n * 512 + k] = f2bf(W3[j]);
        return;
    }
    j -= 512 * 128;
    if (j < E) atomicAdd(&cursor[ei[E + j]], 1);   // histogram of dst
}

// ---------------- CSR scan (self-loops folded: row_ptr[i]=edge_prefix+i) ----

__global__ __launch_bounds__(1024)
void scan_bsum_kernel(const int* __restrict__ cursor, int* __restrict__ bsum, int N) {
    __shared__ int wsum[16];
    int tid = threadIdx.x, lane = tid & 63, w = tid >> 6;
    int i = blockIdx.x * 1024 + tid;
    int v = (i < N) ? cursor[i] : 0;
    #pragma unroll
    for (int off = 32; off; off >>= 1) v += __shfl_xor(v, off, 64);
    if (lane == 0) wsum[w] = v;
    __syncthreads();
    if (tid == 0) {
        int t = 0;
        #pragma unroll
        for (int k = 0; k < 16; ++k) t += wsum[k];
        bsum[blockIdx.x] = t;
    }
}

__global__ __launch_bounds__(1024)
void scan_final_kernel(int* __restrict__ cursor, const int* __restrict__ bsum,
                       int* __restrict__ row_ptr, int N, int NB) {
    __shared__ int wsum[16];
    __shared__ int boff_sh;
    int tid = threadIdx.x, lane = tid & 63, w = tid >> 6;
    if (w == 0) {
        int bv = (lane < NB) ? bsum[lane] : 0;
        int bx = bv;
        #pragma unroll
        for (int off = 1; off < 64; off <<= 1) {
            int t = __shfl_up(bx, off, 64);
            if (lane >= off) bx += t;
        }
        if (lane == blockIdx.x) boff_sh = bx - bv;       // exclusive prefix
        if (blockIdx.x == 0 && lane == 63) row_ptr[N] = bx + N;  // +N self-loops
    }
    int i = blockIdx.x * 1024 + tid;
    int v = (i < N) ? cursor[i] : 0;
    int x = v;
    #pragma unroll
    for (int off = 1; off < 64; off <<= 1) {
        int t = __shfl_up(x, off, 64);
        if (lane >= off) x += t;
    }
    if (lane == 63) wsum[w] = x;
    __syncthreads();
    if (w == 0 && lane < 16) {
        int y = wsum[lane];
        #pragma unroll
        for (int off = 1; off < 16; off <<= 1) {
            int t = __shfl_up(y, off, 64);
            if (lane >= off) y += t;
        }
        wsum[lane] = y;
    }
    __syncthreads();
    int woff = (w == 0) ? 0 : wsum[w - 1];
    int ex = boff_sh + woff + x - v + i;     // + i = self-loop slots
    if (i < N) { row_ptr[i] = ex; cursor[i] = ex; }
}

__global__ __launch_bounds__(256)
void scatter_kernel(const int* __restrict__ ei, int* cursor,
                    int* __restrict__ csr_src, int E, int N) {
    int i = blockIdx.x * 256 + threadIdx.x;
    if (i < E) {
        int s = ei[i], d = ei[E + i];
        int pos = atomicAdd(&cursor[d], 1);
        csr_src[pos] = s;
    } else if (i < E + N) {
        int n = i - E;
        int pos = atomicAdd(&cursor[n], 1);
        csr_src[pos] = n;                // self loop
    }
}

// ---------------- bf16 MFMA GEMM + fused attention dots ----------------
// C[M,Nn]bf16 = A[M,K]bf16 @ BT[Nn,K]^T. TMxTN tile, BK=64, 8 waves (512 thr),
// 64x64 wave tiles. A+B staged into one LDS buffer (rows 0..TM-1 = A,
// TM..TM+TN-1 = B) via global_load_lds 16B/lane; phys seg = seg ^ (row&7)
// keeps both staging and b128 frag reads bank-minimal. Widened tiles halve
// per-output staging bytes vs 128x128 (short-K GEMMs are staging-bound).
// Epilogue computes a_src/a_dst for the TN/128 heads this block covers.
// [History: R7 LDS-free regressed; R10 BK=64 only +7us -> drains not dominant]

template<int TM, int TN>
__global__ __launch_bounds__(512)
void mfma_gemm_kernel(const unsigned short* __restrict__ A,
                      const unsigned short* __restrict__ BT,
                      unsigned short* __restrict__ C,
                      const float* __restrict__ att_src,
                      const float* __restrict__ att_dst,
                      float* __restrict__ a_srcO, float* __restrict__ a_dstO,
                      int H, int M, int Nn, int K) {
    constexpr int NH = TN / 128;               // heads per block
    __shared__ unsigned short buf[(TM + TN) * 64];    // 48 KB
    __shared__ float psum[TN / 64][TM];
    __shared__ float pdsum[TN / 64][TM];
    const int tid = threadIdx.x;
    const int m0 = blockIdx.y * TM;
    const int n0 = blockIdx.x * TN;
    const int head_base = blockIdx.x * NH;
    const int lane = tid & 63, wave = tid >> 6;        // wave 0..7
    const int wm = (wave & (TM / 64 - 1)) * 64;
    const int wn = (wave / (TM / 64)) * 64;
    const int quad = lane >> 4, rr = lane & 15;

    // staging: 8 waves x 6 insts x 8 rows = 384 rows (TM A-rows + TN B-rows)
    const int srow = lane >> 3;                // row within 8-row group
    const int sseg = (lane & 7) ^ srow;        // logical 8-elem seg to fetch
    const unsigned short* gptr[6];
    unsigned short* lptr[6];
    #pragma unroll
    for (int j = 0; j < 6; ++j) {
        int base_row = wave * 48 + j * 8;      // multiple of 8; A/B uniform
        lptr[j] = buf + base_row * 64;
        if (base_row < TM) {
            int gr = min(m0 + base_row + srow, M - 1);
            gptr[j] = A + (size_t)gr * K;
        } else {
            int gr = n0 + (base_row - TM) + srow;
            gptr[j] = BT + (size_t)gr * K;
        }
    }

    floatx4 acc[4][4] = {};

    for (int k0 = 0; k0 < K; k0 += 64) {
        #pragma unroll
        for (int j = 0; j < 6; ++j)
            async_copy16(gptr[j] + k0 + sseg * 8, lptr[j]);
        __syncthreads();

        #pragma unroll
        for (int k32 = 0; k32 < 2; ++k32) {
            short8 af[4], bf[4];
            #pragma unroll
            for (int mi = 0; mi < 4; ++mi) {
                int row = wm + mi * 16 + rr;
                int phys = (k32 * 4 + quad) ^ (rr & 7);
                af[mi] = *(const short8*)(buf + row * 64 + phys * 8);
            }
            #pragma unroll
            for (int ni = 0; ni < 4; ++ni) {
                int row = TM + wn + ni * 16 + rr;
                int phys = (k32 * 4 + quad) ^ (rr & 7);
                bf[ni] = *(const short8*)(buf + row * 64 + phys * 8);
            }
            #pragma unroll
            for (int mi = 0; mi < 4; ++mi)
                #pragma unroll
                for (int ni = 0; ni < 4; ++ni)
                    acc[mi][ni] = __builtin_amdgcn_mfma_f32_16x16x32_bf16(
                        af[mi], bf[ni], acc[mi][ni], 0, 0, 0);
        }
        __syncthreads();
    }

    // ---- h store (bf16), C/D layout: col=lane&15, row=quad*4+reg ----
    #pragma unroll
    for (int mi = 0; mi < 4; ++mi) {
        #pragma unroll
        for (int ni = 0; ni < 4; ++ni) {
            int col = n0 + wn + ni * 16 + rr;
            #pragma unroll
            for (int r = 0; r < 4; ++r) {
                int row = m0 + wm + mi * 16 + quad * 4 + r;
                if (row < M) C[(size_t)row * Nn + col] = f2bf(acc[mi][ni][r]);
            }
        }
    }

    // ---- fused attention dots (per covered head) ----
    float ats[4], atd[4];
    #pragma unroll
    for (int ni = 0; ni < 4; ++ni) {
        int cc = wn + ni * 16;                  // col within block tile
        int h = head_base + (cc >> 7);
        int c = (cc + rr) & 127;                // channel within head
        ats[ni] = att_src[h * 128 + c];
        atd[ni] = att_dst[h * 128 + c];
    }
    const int wg = wn >> 6;                     // wave column group
    #pragma unroll
    for (int mi = 0; mi < 4; ++mi) {
        #pragma unroll
        for (int r = 0; r < 4; ++r) {
            float ps = 0.f, pd = 0.f;
            #pragma unroll
            for (int ni = 0; ni < 4; ++ni) {
                ps += ats[ni] * acc[mi][ni][r];
                pd += atd[ni] * acc[mi][ni][r];
            }
            #pragma unroll
            for (int off = 1; off < 16; off <<= 1) {
                ps += __shfl_xor(ps, off, 64);
                pd += __shfl_xor(pd, off, 64);
            }
            if (rr == 0) {
                int row = wm + mi * 16 + quad * 4 + r;   // local row
                psum[wg][row] = ps;
                pdsum[wg][row] = pd;
            }
        }
    }
    __syncthreads();
    if (tid < NH * TM) {
        int h = tid / TM, r = tid % TM;
        int gr = m0 + r;
        if (gr < M) {
            a_srcO[(size_t)gr * H + head_base + h] = psum[2 * h][r] + psum[2 * h + 1][r];
            a_dstO[(size_t)gr * H + head_base + h] = pdsum[2 * h][r] + pdsum[2 * h + 1][r];
        }
    }
}

// ---------------- per-dst-node softmax + aggregation (R6 version) -----------
// One WAVE per dst node. Single pass: exp(e) without max subtraction (logits
// O(1): identical ratio, fp32-safe). Depth-4 pipelined row gathers (16B/lane);
// scalarized CSR chain. No LDS/barriers. At the pattern wall (~75us):
// FETCH = 8 XCDs x table = compulsory floor; ~3.7 TB/s fabric rate invariant
// across R5/R6/R8/R10 variants (depth-4 neutral, head-slice regressed).

template<int F, int H, bool RELU, bool BF16OUT>
__global__ __launch_bounds__(256)
void agg_kernel(const unsigned* __restrict__ hfeat, const float* __restrict__ a_src,
                const float* __restrict__ a_dst, const int* __restrict__ row_ptr,
                const int* __restrict__ csr_src, const float* __restrict__ bias,
                void* __restrict__ out_v, int N) {
    constexpr int UPL = F / 128;             // uints per lane: 4 or 1
    constexpr int RU = F / 2;                // uints per row
    const int wave = threadIdx.x >> 6, lane = threadIdx.x & 63;
    const int n = blockIdx.x * 4 + wave;
    if (n >= N) return;
    const int begin = __builtin_amdgcn_readfirstlane(row_ptr[n]);
    const int deg = __builtin_amdgcn_readfirstlane(row_ptr[n + 1]) - begin;
    const int myh = (2 * UPL * lane) / 128;
    const float adst = a_dst[n * H + myh];

    float acc[2 * UPL];
    #pragma unroll
    for (int j = 0; j < 2 * UPL; ++j) acc[j] = 0.f;
    float dacc = 0.f;

    unsigned u0[UPL], u1[UPL], u2[UPL], u3[UPL];
    float av0 = 0.f, av1 = 0.f, av2 = 0.f, av3 = 0.f;

#define LOADSLOT(idx, U, AV)                                              \
    {                                                                     \
        int s_ = __builtin_amdgcn_readfirstlane(csr_src[begin + (idx)]);  \
        if (UPL == 4) {                                                   \
            uint4 t_ = ((const uint4*)(hfeat + (size_t)s_ * RU))[lane];   \
            U[0] = t_.x; U[1] = t_.y; U[2] = t_.z; U[3] = t_.w;           \
        } else {                                                          \
            U[0] = hfeat[(size_t)s_ * RU + lane];                         \
        }                                                                 \
        AV = a_src[s_ * H + myh];                                         \
    }

#define CONSUME(U, AV)                                                    \
    {                                                                     \
        float e_ = AV + adst;                                             \
        e_ = e_ > 0.f ? e_ : NEG_SLOPE * e_;                              \
        float ex_ = __expf(e_);                                           \
        dacc += ex_;                                                      \
        _Pragma("unroll")                                                 \
        for (int q_ = 0; q_ < UPL; ++q_) {                                \
            acc[2 * q_]     += ex_ * bf2f_lo(U[q_]);                      \
            acc[2 * q_ + 1] += ex_ * bf2f_hi(U[q_]);                      \
        }                                                                 \
    }

    LOADSLOT(0, u0, av0);
    if (deg > 1) LOADSLOT(1, u1, av1);
    if (deg > 2) LOADSLOT(2, u2, av2);
    if (deg > 3) LOADSLOT(3, u3, av3);
    int i = 0;
    for (; i + 8 <= deg; i += 4) {
        CONSUME(u0, av0); LOADSLOT(i + 4, u0, av0);
        CONSUME(u1, av1); LOADSLOT(i + 5, u1, av1);
        CONSUME(u2, av2); LOADSLOT(i + 6, u2, av2);
        CONSUME(u3, av3); LOADSLOT(i + 7, u3, av3);
    }
    int rem = deg - i;                       // 1..7
    CONSUME(u0, av0); if (rem > 4) LOADSLOT(i + 4, u0, av0);
    if (rem > 1) { CONSUME(u1, av1); if (rem > 5) LOADSLOT(i + 5, u1, av1); }
    if (rem > 2) { CONSUME(u2, av2); if (rem > 6) LOADSLOT(i + 6, u2, av2); }
    if (rem > 3) CONSUME(u3, av3);
    if (rem > 4) CONSUME(u0, av0);
    if (rem > 5) CONSUME(u1, av1);
    if (rem > 6) CONSUME(u2, av2);
#undef LOADSLOT
#undef CONSUME

    float inv = 1.f / dacc;
    const int cb = 2 * UPL * lane;
    if (BF16OUT) {
        unsigned pk[UPL];
        #pragma unroll
        for (int q = 0; q < UPL; ++q) {
            float v0 = acc[2 * q] * inv + bias[cb + 2 * q];
            float v1 = acc[2 * q + 1] * inv + bias[cb + 2 * q + 1];
            if (RELU) { v0 = fmaxf(v0, 0.f); v1 = fmaxf(v1, 0.f); }
            pk[q] = (unsigned)f2bf(v0) | ((unsigned)f2bf(v1) << 16);
        }
        if (UPL == 4) {
            uint4 t; t.x = pk[0]; t.y = pk[1]; t.z = pk[2]; t.w = pk[3];
            ((uint4*)((unsigned*)out_v + (size_t)n * RU))[lane] = t;
        } else {
            ((unsigned*)out_v)[(size_t)n * RU + lane] = pk[0];
        }
    } else {
        #pragma unroll
        for (int q = 0; q < UPL; ++q) {
            float v0 = acc[2 * q] * inv + bias[cb + 2 * q];
            float v1 = acc[2 * q + 1] * inv + bias[cb + 2 * q + 1];
            if (RELU) { v0 = fmaxf(v0, 0.f); v1 = fmaxf(v1, 0.f); }
            float2 o; o.x = v0; o.y = v1;
            ((float2*)((float*)out_v + (size_t)n * F))[UPL * lane + q] = o;
        }
    }
}

// ---------------- host launch ----------------

extern "C" void kernel_launch(void* const* d_in, const int* in_sizes, int n_in,
                              void* d_out, int out_size, void* d_ws, size_t ws_size,
                              hipStream_t stream) {
    const float* x        = (const float*)d_in[0];
    const int*   ei       = (const int*)  d_in[1];
    const float* W1       = (const float*)d_in[2];
    const float* att_src1 = (const float*)d_in[3];
    const float* att_dst1 = (const float*)d_in[4];
    const float* b1       = (const float*)d_in[5];
    const float* W2       = (const float*)d_in[6];
    const float* att_src2 = (const float*)d_in[7];
    const float* att_dst2 = (const float*)d_in[8];
    const float* b2       = (const float*)d_in[9];
    const float* W3       = (const float*)d_in[10];
    const float* att_src3 = (const float*)d_in[11];
    const float* att_dst3 = (const float*)d_in[12];
    const float* b3       = (const float*)d_in[13];

    const int IN_FEATS = 256;
    const int N = in_sizes[0] / IN_FEATS;   // 30000
    const int E = in_sizes[1] / 2;          // 480000
    const int ET = E + N;
    const int NB = (N + 1023) / 1024;       // scan blocks (30)

    // workspace layout
    char* p = (char*)d_ws;
    unsigned short* h_bf    = (unsigned short*)p; p += (size_t)N * 512 * sizeof(unsigned short);
    unsigned short* act_bf  = (unsigned short*)p; p += (size_t)N * 512 * sizeof(unsigned short);
    unsigned short* x_bf    = (unsigned short*)p; p += (size_t)N * 256 * sizeof(unsigned short);
    float*          a_src   = (float*)p;          p += (size_t)N * 4 * sizeof(float);
    float*          a_dst   = (float*)p;          p += (size_t)N * 4 * sizeof(float);
    unsigned short* W1T     = (unsigned short*)p; p += (size_t)512 * 256 * sizeof(unsigned short);
    unsigned short* W2T     = (unsigned short*)p; p += (size_t)512 * 512 * sizeof(unsigned short);
    unsigned short* W3T     = (unsigned short*)p; p += (size_t)128 * 512 * sizeof(unsigned short);
    int*            row_ptr = (int*)p;            p += ((size_t)N + 16) * sizeof(int);
    int*            cursor  = (int*)p;            p += ((size_t)N + 16) * sizeof(int);
    int*            bsum    = (int*)p;            p += 64 * sizeof(int);
    int*            csr_src = (int*)p;            p += (size_t)ET * sizeof(int);

    // ---- prep (x cast + W transposes + hist) + CSR build ----
    hipMemsetAsync(cursor, 0, (size_t)N * sizeof(int), stream);
    {
        int n4 = N * 256 / 4;
        int total = n4 + 256 * 512 + 512 * 512 + 512 * 128 + E;
        prep_hist_kernel<<<(total + 255) / 256, 256, 0, stream>>>(
            x, x_bf, W1, W1T, W2, W2T, W3, W3T, ei, cursor, n4, E);
    }
    scan_bsum_kernel<<<NB, 1024, 0, stream>>>(cursor, bsum, N);
    scan_final_kernel<<<NB, 1024, 0, stream>>>(cursor, bsum, row_ptr, N, NB);
    scatter_kernel<<<(E + N + 255) / 256, 256, 0, stream>>>(ei, cursor, csr_src, E, N);

    const int MB128 = (N + 127) / 128;      // 235
    const int MB256 = (N + 255) / 256;      // 118
    const int NB4 = (N + 3) / 4;

    // ---- Layer 1: 256 -> 4x128 concat + relu (h bf16) ----
    mfma_gemm_kernel<128, 256><<<dim3(2, MB128), 512, 0, stream>>>(x_bf, W1T, h_bf, att_src1, att_dst1, a_src, a_dst, 4, N, 512, 256);
    agg_kernel<512, 4, true, true><<<NB4, 256, 0, stream>>>((const unsigned*)h_bf, a_src, a_dst, row_ptr, csr_src, b1, act_bf, N);

    // ---- Layer 2: 512 -> 4x128 concat + relu (h bf16) ----
    mfma_gemm_kernel<128, 256><<<dim3(2, MB128), 512, 0, stream>>>(act_bf, W2T, h_bf, att_src2, att_dst2, a_src, a_dst, 4, N, 512, 512);
    agg_kernel<512, 4, true, true><<<NB4, 256, 0, stream>>>((const unsigned*)h_bf, a_src, a_dst, row_ptr, csr_src, b2, act_bf, N);

    // ---- Layer 3: 512 -> 1x128 (h bf16), fp32 out, no relu ----
    mfma_gemm_kernel<256, 128><<<dim3(1, MB256), 512, 0, stream>>>(act_bf, W3T, h_bf, att_src3, att_dst3, a_src, a_dst, 1, N, 128, 512);
    agg_kernel<128, 1, false, false><<<NB4, 256, 0, stream>>>((const unsigned*)h_bf, a_src, a_dst, row_ptr, csr_src, b3, d_out, N);
}